// Round 3
// baseline (1245.077 us; speedup 1.0000x reference)
//
#include <hip/hip_runtime.h>
#include <hip/hip_bf16.h>

typedef __attribute__((ext_vector_type(8))) short bf16x8;   // 8 bf16 = 4 VGPRs
typedef __attribute__((ext_vector_type(4))) float f32x4;    // 4 f32 acc

static __device__ __forceinline__ float bf2f(__hip_bfloat16 v) { return __bfloat162float(v); }

static __device__ __forceinline__ float bs2f(short s) {
    unsigned u = ((unsigned)(unsigned short)s) << 16;
    float f; __builtin_memcpy(&f, &u, 4); return f;
}
static __device__ __forceinline__ short f2bs(float v) {
    __hip_bfloat16 b = __float2bfloat16(v);
    short s; __builtin_memcpy(&s, &b, 2); return s;
}
// read element i of a float array that is either f32 or bf16
static __device__ __forceinline__ float loadf(const void* p, int i, bool f32) {
    if (f32) return ((const float*)p)[i];
    return bf2f(((const __hip_bfloat16*)p)[i]);
}

// ------------------------------------------------- runtime dtype detection
// flags[0] = 1 if edge_index is int64 (odd 32-bit words of first 2048 pairs all 0)
// flags[1] = 1 if float inputs are f32 (bf16 view of x has huge-exponent lanes)
__global__ __launch_bounds__(256) void detect_kernel(const unsigned* __restrict__ ew,
        const unsigned short* __restrict__ xw, int* __restrict__ flags) {
    __shared__ int s_odd, s_f32;
    int t = threadIdx.x;
    if (t == 0) { s_odd = 0; s_f32 = 0; }
    __syncthreads();
    unsigned acc = 0;
    for (int i = t; i < 2048; i += 256) acc |= ew[2 * i + 1];
    if (acc) atomicOr(&s_odd, 1);
    int f32ev = 0;
    for (int i = t; i < 4096; i += 256) {
        unsigned e = (xw[i] >> 7) & 0xFF;          // bf16 exponent field
        if (e >= 0xC0) f32ev = 1;                  // |v| >= 2^65: impossible for real bf16 data
    }
    if (f32ev) atomicOr(&s_f32, 1);
    __syncthreads();
    if (t == 0) { flags[0] = s_odd ? 0 : 1; flags[1] = s_f32; }
}

// decode edge_index (int32 or int64 layout) into canonical int32 src/dst
__global__ void decode_edges(const unsigned* __restrict__ ew, int E,
        const int* __restrict__ flags, int* __restrict__ src, int* __restrict__ dst) {
    int e = blockIdx.x * blockDim.x + threadIdx.x;
    if (e >= E) return;
    if (flags[0]) {      // int64: words [2e] lo; dst row starts at word 2E
        src[e] = (int)ew[2 * (size_t)e];
        dst[e] = (int)ew[2 * (size_t)E + 2 * (size_t)e];
    } else {
        src[e] = (int)ew[e];
        dst[e] = (int)ew[(size_t)E + e];
    }
}

// ---------------------------------------------------------------- CSR build
__global__ void deg_kernel(const int* __restrict__ dst, int* __restrict__ deg, int E) {
    int e = blockIdx.x * blockDim.x + threadIdx.x;
    if (e < E) atomicAdd(&deg[dst[e]], 1);
}

__global__ __launch_bounds__(1024) void scan_kernel(const int* __restrict__ deg,
        int* __restrict__ rowptr, int* __restrict__ cursor, int N) {
    __shared__ int part[1024];
    int t = threadIdx.x;
    int chunk = (N + 1023) >> 10;
    int s0 = t * chunk;
    int e0 = min(s0 + chunk, N);
    int sum = 0;
    for (int i = s0; i < e0; ++i) sum += deg[i];
    part[t] = sum;
    __syncthreads();
    for (int off = 1; off < 1024; off <<= 1) {
        int v = (t >= off) ? part[t - off] : 0;
        __syncthreads();
        part[t] += v;
        __syncthreads();
    }
    int run = part[t] - sum;          // exclusive prefix of this thread's chunk
    for (int i = s0; i < e0; ++i) { rowptr[i] = run; cursor[i] = run; run += deg[i]; }
    if (t == 1023) rowptr[N] = part[1023];
}

__global__ void bucket_kernel(const int* __restrict__ src, const int* __restrict__ dst,
        int* __restrict__ cursor, int* __restrict__ ebuf, int E) {
    int e = blockIdx.x * blockDim.x + threadIdx.x;
    if (e < E) {
        int p = atomicAdd(&cursor[dst[e]], 1);
        ebuf[p] = src[e];
    }
}

// ------------------------------------------------------- weight pre-transpose
// Wt[fo*ldt + fi] = W[fi*cols + fo], output canonical bf16
__global__ void transpose_kernel(const void* __restrict__ W,
        __hip_bfloat16* __restrict__ Wt, int rows, int cols, int ldt,
        const int* __restrict__ flags) {
    int idx = blockIdx.x * blockDim.x + threadIdx.x;
    if (idx < rows * cols) {
        int fi = idx / cols, fo = idx % cols;
        Wt[fo * ldt + fi] = __float2bfloat16(loadf(W, idx, flags[1] != 0));
    }
}

// --------------------------------------------------------------- MFMA GEMM
static __device__ __forceinline__ bf16x8 load_frag(const void* X, size_t off, bool f32) {
    if (!f32) return *(const bf16x8*)((const __hip_bfloat16*)X + off);
    const float* p = (const float*)X + off;
    float4 a = *(const float4*)p;
    float4 b = *(const float4*)(p + 4);
    bf16x8 r;
    r[0] = f2bs(a.x); r[1] = f2bs(a.y); r[2] = f2bs(a.z); r[3] = f2bs(a.w);
    r[4] = f2bs(b.x); r[5] = f2bs(b.y); r[6] = f2bs(b.z); r[7] = f2bs(b.w);
    return r;
}

// out[node][fo] = sum_k X[node][k] * Wt[fo][k]  (+bias[fo]); out bf16 or f32 (out_f32).
// X split at K0 between X0/X1. One wave = 16-node stripe x all Ncols.
__global__ __launch_bounds__(256) void gemm_mfma(
        const void* __restrict__ X0, const void* __restrict__ X1, int K0, int K, int xflag,
        const __hip_bfloat16* __restrict__ Wt, const void* __restrict__ bias,
        void* __restrict__ outp, int ldo, int out_f32, int M, int Ncols,
        const int* __restrict__ flags) {
    bool pf = flags[1] != 0;       // raw float inputs are f32
    bool xf32 = (xflag != 0) && pf;
    int wave = (blockIdx.x * blockDim.x + threadIdx.x) >> 6;
    int node_base = wave << 4;
    if (node_base >= M) return;
    int lane = threadIdx.x & 63;
    int quad = lane >> 4;          // 0..3
    int r = lane & 15;             // 0..15
    int node = node_base + r;
    int nodeL = min(node, M - 1);  // clamp for loads
    int ksteps = K >> 5;           // K/32, max 8

    bf16x8 xf[8];
    #pragma unroll
    for (int ks = 0; ks < 8; ++ks) {
        if (ks >= ksteps) break;
        int k = ks * 32 + quad * 8;
        if (k < K0) xf[ks] = load_frag(X0, (size_t)nodeL * K0 + k, xf32);
        else        xf[ks] = load_frag(X1, (size_t)nodeL * (K - K0) + (k - K0), xf32);
    }

    int ntiles = Ncols >> 4;
    for (int ft = 0; ft < ntiles; ++ft) {
        f32x4 acc = {0.f, 0.f, 0.f, 0.f};
        const __hip_bfloat16* wrow = Wt + (size_t)(ft * 16 + r) * K + quad * 8;
        #pragma unroll
        for (int ks = 0; ks < 8; ++ks) {
            if (ks >= ksteps) break;
            bf16x8 wf = *(const bf16x8*)(wrow + ks * 32);
            acc = __builtin_amdgcn_mfma_f32_16x16x32_bf16(wf, xf[ks], acc, 0, 0, 0);
        }
        // D layout: col = lane&15 -> node r, row = quad*4 + reg -> fo
        int fo = ft * 16 + quad * 4;
        float b0 = 0.f, b1 = 0.f, b2 = 0.f, b3 = 0.f;
        if (bias) {
            b0 = loadf(bias, fo + 0, pf); b1 = loadf(bias, fo + 1, pf);
            b2 = loadf(bias, fo + 2, pf); b3 = loadf(bias, fo + 3, pf);
        }
        if (node < M) {
            if (out_f32) {
                float4 res;
                res.x = acc[0] + b0; res.y = acc[1] + b1;
                res.z = acc[2] + b2; res.w = acc[3] + b3;
                *(float4*)((float*)outp + (size_t)node * ldo + fo) = res;
            } else {
                short4 res;
                res.x = f2bs(acc[0] + b0); res.y = f2bs(acc[1] + b1);
                res.z = f2bs(acc[2] + b2); res.w = f2bs(acc[3] + b3);
                *(short4*)((short*)outp + (size_t)node * ldo + fo) = res;
            }
        }
    }
}

// --------------------------------------- fused mean-agg + bias + lin_r + LN + ReLU
// yz bf16 [N][256]: cols 0..127 = y (projected neighbor feats), 128..255 = z (lin_r)
// One wave per node; lane handles features 2*lane, 2*lane+1. f32 accumulation.
__global__ __launch_bounds__(256) void agg_ln_relu(
        const __hip_bfloat16* __restrict__ yz, const int* __restrict__ rowptr,
        const int* __restrict__ ebuf,
        const void* __restrict__ bn, const void* __restrict__ g,
        const void* __restrict__ be, __hip_bfloat16* __restrict__ hout, int N,
        const int* __restrict__ flags) {
    int node = (blockIdx.x * blockDim.x + threadIdx.x) >> 6;
    if (node >= N) return;
    bool pf = flags[1] != 0;
    int lane = threadIdx.x & 63;
    int f = lane * 2;
    const short* yzs = (const short*)yz;
    int start = rowptr[node], end = rowptr[node + 1];
    float a0 = 0.f, a1 = 0.f;
    for (int i = start; i < end; ++i) {
        int s = ebuf[i];                          // wave-uniform load
        short2 t = *(const short2*)(yzs + (size_t)s * 256 + f);
        a0 += bs2f(t.x); a1 += bs2f(t.y);
    }
    float inv = 1.f / fmaxf((float)(end - start), 1.f);
    short2 zt = *(const short2*)(yzs + (size_t)node * 256 + 128 + f);
    float v0 = a0 * inv + loadf(bn, f, pf)     + bs2f(zt.x);
    float v1 = a1 * inv + loadf(bn, f + 1, pf) + bs2f(zt.y);
    float s = v0 + v1;
    #pragma unroll
    for (int off = 32; off > 0; off >>= 1) s += __shfl_xor(s, off, 64);
    float mu = s * (1.f / 128.f);
    float d0 = v0 - mu, d1 = v1 - mu;
    float q = d0 * d0 + d1 * d1;
    #pragma unroll
    for (int off = 32; off > 0; off >>= 1) q += __shfl_xor(q, off, 64);
    float rstd = rsqrtf(q * (1.f / 128.f) + 1e-5f);
    float o0 = fmaxf(d0 * rstd * loadf(g, f, pf)     + loadf(be, f, pf),     0.f);
    float o1 = fmaxf(d1 * rstd * loadf(g, f + 1, pf) + loadf(be, f + 1, pf), 0.f);
    short* hp = (short*)hout + (size_t)node * 128 + f;
    hp[0] = f2bs(o0);
    hp[1] = f2bs(o1);
}

// ------------------------------------------------------------- MLP head
// out = relu(feats @ Wh1 + bh1) @ Wh2 + bh2, feats f32 [N][128]
// output dtype follows flags[1]: f32 if inputs f32, else bf16
__global__ __launch_bounds__(256) void head_kernel(
        const float* __restrict__ feats, const void* __restrict__ Wh1,
        const void* __restrict__ bh1, const void* __restrict__ Wh2,
        const void* __restrict__ bh2, void* __restrict__ outp, int N,
        const int* __restrict__ flags) {
    __shared__ float sfe[8 * 128];
    __shared__ float shid[8 * 32];
    bool pf = flags[1] != 0;
    int nb = blockIdx.x * 8;
    int tid = threadIdx.x;
    {
        int i = tid * 4;
        int gnode = nb + (i >> 7);
        float4 v = make_float4(0.f, 0.f, 0.f, 0.f);
        if (gnode < N) v = *(const float4*)(feats + (size_t)gnode * 128 + (i & 127));
        *(float4*)(sfe + i) = v;
    }
    __syncthreads();
    {
        int nloc = tid >> 5, col = tid & 31;
        float acc = loadf(bh1, col, pf);
        const float* fr = sfe + nloc * 128;
        #pragma unroll 8
        for (int k = 0; k < 128; ++k) acc += fr[k] * loadf(Wh1, k * 32 + col, pf);
        shid[nloc * 32 + col] = fmaxf(acc, 0.f);
    }
    __syncthreads();
    if (tid < 128) {
        int nloc = tid >> 4, col = tid & 15;
        int gnode = nb + nloc;
        if (gnode < N) {
            float acc = loadf(bh2, col, pf);
            const float* hr = shid + nloc * 32;
            #pragma unroll
            for (int k = 0; k < 32; ++k) acc += hr[k] * loadf(Wh2, k * 16 + col, pf);
            if (pf) ((float*)outp)[(size_t)gnode * 16 + col] = acc;
            else    ((__hip_bfloat16*)outp)[(size_t)gnode * 16 + col] = __float2bfloat16(acc);
        }
    }
}

// ---------------------------------------------------------------- launcher
extern "C" void kernel_launch(void* const* d_in, const int* in_sizes, int n_in,
                              void* d_out, int out_size, void* d_ws, size_t ws_size,
                              hipStream_t stream) {
    const void* x    = d_in[0];
    const unsigned* ei = (const unsigned*)d_in[1];
    const void* Wnl0 = d_in[2];
    const void* bnl0 = d_in[3];
    const void* Wr0  = d_in[4];
    const void* Wnl1 = d_in[5];
    const void* bnl1 = d_in[6];
    const void* Wr1  = d_in[7];
    const void* g0   = d_in[8];
    const void* be0  = d_in[9];
    const void* g1   = d_in[10];
    const void* be1  = d_in[11];
    const void* Wjk  = d_in[12];
    const void* bjk  = d_in[13];
    const void* Wh1  = d_in[14];
    const void* bh1  = d_in[15];
    const void* Wh2  = d_in[16];
    const void* bh2  = d_in[17];

    const int N = in_sizes[0] / 256;
    const int E = in_sizes[1] / 2;

    char* ws = (char*)d_ws;
    size_t off = 0;
    auto alloc = [&](size_t bytes) -> void* {
        void* p = ws + off;
        off = (off + bytes + 255) & ~(size_t)255;
        return p;
    };
    int* flags  = (int*)alloc(256);
    int* src    = (int*)alloc((size_t)E * 4);
    int* dst    = (int*)alloc((size_t)E * 4);
    int* rowptr = (int*)alloc((size_t)(N + 1) * 4);
    int* deg    = (int*)alloc((size_t)N * 4);
    int* cursor = (int*)alloc((size_t)N * 4);
    int* ebuf   = (int*)alloc((size_t)E * 4);
    __hip_bfloat16* Wt0  = (__hip_bfloat16*)alloc(256 * 256 * 2);
    __hip_bfloat16* Wt1  = (__hip_bfloat16*)alloc(256 * 128 * 2);
    __hip_bfloat16* Wtjk = (__hip_bfloat16*)alloc(128 * 256 * 2);
    __hip_bfloat16* yz = (__hip_bfloat16*)alloc((size_t)N * 256 * 2);   // also feats f32 [N][128]
    __hip_bfloat16* h0 = (__hip_bfloat16*)alloc((size_t)N * 128 * 2);
    __hip_bfloat16* h1 = (__hip_bfloat16*)alloc((size_t)N * 128 * 2);
    float* feats = (float*)yz;   // yz dead after second agg; same byte size

    // dtype detection + canonical edge decode
    detect_kernel<<<1, 256, 0, stream>>>(ei, (const unsigned short*)x, flags);
    int eb = (E + 255) / 256;
    decode_edges<<<eb, 256, 0, stream>>>(ei, E, flags, src, dst);

    // CSR build
    (void)hipMemsetAsync(deg, 0, (size_t)N * 4, stream);
    deg_kernel<<<eb, 256, 0, stream>>>(dst, deg, E);
    scan_kernel<<<1, 1024, 0, stream>>>(deg, rowptr, cursor, N);
    bucket_kernel<<<eb, 256, 0, stream>>>(src, dst, cursor, ebuf, E);

    // Weight transposes: Wt0 = [Wnl0^T ; Wr0^T] (256 rows x K=256),
    // Wt1 = [Wnl1^T ; Wr1^T] (256 rows x K=128), Wtjk = Wjk^T (128 rows x K=256)
    transpose_kernel<<<(256 * 128 + 255) / 256, 256, 0, stream>>>(Wnl0, Wt0, 256, 128, 256, flags);
    transpose_kernel<<<(256 * 128 + 255) / 256, 256, 0, stream>>>(Wr0,  Wt0 + 128 * 256, 256, 128, 256, flags);
    transpose_kernel<<<(128 * 128 + 255) / 256, 256, 0, stream>>>(Wnl1, Wt1, 128, 128, 128, flags);
    transpose_kernel<<<(128 * 128 + 255) / 256, 256, 0, stream>>>(Wr1,  Wt1 + 128 * 128, 128, 128, 128, flags);
    transpose_kernel<<<(256 * 128 + 255) / 256, 256, 0, stream>>>(Wjk,  Wtjk, 256, 128, 256, flags);

    int gwaves = (N + 15) / 16;
    int gblocks = (gwaves * 64 + 255) / 256;
    int ablocks = (int)(((size_t)N * 64 + 255) / 256);

    // layer 0: project (y0 = x@Wnl0, z0 = x@Wr0) -> agg+LN+ReLU -> h0
    gemm_mfma<<<gblocks, 256, 0, stream>>>(x, x, 256, 256, 1, Wt0, nullptr, yz, 256, 0, N, 256, flags);
    agg_ln_relu<<<ablocks, 256, 0, stream>>>(yz, rowptr, ebuf, bnl0, g0, be0, h0, N, flags);

    // layer 1
    gemm_mfma<<<gblocks, 256, 0, stream>>>(h0, h0, 128, 128, 0, Wt1, nullptr, yz, 256, 0, N, 256, flags);
    agg_ln_relu<<<ablocks, 256, 0, stream>>>(yz, rowptr, ebuf, bnl1, g1, be1, h1, N, flags);

    // JK: feats = [h0|h1] @ Wjk + bjk   (K split 128/128), f32 output
    gemm_mfma<<<gblocks, 256, 0, stream>>>(h0, h1, 128, 256, 0, Wtjk, bjk, feats, 128, 1, N, 128, flags);

    // MLP head (output dtype follows detected float dtype)
    head_kernel<<<(N + 7) / 8, 256, 0, stream>>>(feats, Wh1, bh1, Wh2, bh2, d_out, N, flags);
}

// Round 4
// 1028.534 us; speedup vs baseline: 1.2105x; 1.2105x over previous
//
#include <hip/hip_runtime.h>
#include <hip/hip_bf16.h>

typedef __attribute__((ext_vector_type(8))) short bf16x8;   // 8 bf16 = 4 VGPRs
typedef __attribute__((ext_vector_type(4))) float f32x4;    // 4 f32 acc

static __device__ __forceinline__ float bf2f(__hip_bfloat16 v) { return __bfloat162float(v); }

static __device__ __forceinline__ float bs2f(short s) {
    unsigned u = ((unsigned)(unsigned short)s) << 16;
    float f; __builtin_memcpy(&f, &u, 4); return f;
}
static __device__ __forceinline__ short f2bs(float v) {
    __hip_bfloat16 b = __float2bfloat16(v);
    short s; __builtin_memcpy(&s, &b, 2); return s;
}
// read element i of a float array that is either f32 or bf16
static __device__ __forceinline__ float loadf(const void* p, int i, bool f32) {
    if (f32) return ((const float*)p)[i];
    return bf2f(((const __hip_bfloat16*)p)[i]);
}

// ------------------------------------------------- runtime dtype detection
// flags[0] = 1 if edge_index is int64 (odd 32-bit words of first 2048 pairs all 0)
// flags[1] = 1 if float inputs are f32 (bf16 view of x has huge-exponent lanes)
__global__ __launch_bounds__(256) void detect_kernel(const unsigned* __restrict__ ew,
        const unsigned short* __restrict__ xw, int* __restrict__ flags) {
    __shared__ int s_odd, s_f32;
    int t = threadIdx.x;
    if (t == 0) { s_odd = 0; s_f32 = 0; }
    __syncthreads();
    unsigned acc = 0;
    for (int i = t; i < 2048; i += 256) acc |= ew[2 * i + 1];
    if (acc) atomicOr(&s_odd, 1);
    int f32ev = 0;
    for (int i = t; i < 4096; i += 256) {
        unsigned e = (xw[i] >> 7) & 0xFF;          // bf16 exponent field
        if (e >= 0xC0) f32ev = 1;                  // impossible for real bf16 data
    }
    if (f32ev) atomicOr(&s_f32, 1);
    __syncthreads();
    if (t == 0) { flags[0] = s_odd ? 0 : 1; flags[1] = s_f32; }
}

// decode edge_index (int32 or int64 layout) into canonical int32 src/dst
__global__ void decode_edges(const unsigned* __restrict__ ew, int E,
        const int* __restrict__ flags, int* __restrict__ src, int* __restrict__ dst) {
    int e = blockIdx.x * blockDim.x + threadIdx.x;
    if (e >= E) return;
    if (flags[0]) {      // int64: words [2e] lo; dst row starts at word 2E
        src[e] = (int)ew[2 * (size_t)e];
        dst[e] = (int)ew[2 * (size_t)E + 2 * (size_t)e];
    } else {
        src[e] = (int)ew[e];
        dst[e] = (int)ew[(size_t)E + e];
    }
}

// ---------------------------------------------------------------- CSR build
__global__ void deg_kernel(const int* __restrict__ dst, int* __restrict__ deg, int E) {
    int e = blockIdx.x * blockDim.x + threadIdx.x;
    if (e < E) atomicAdd(&deg[dst[e]], 1);
}

// ---- 3-phase multi-block exclusive scan (512 elements per block) ----
// A: per-block sum
__global__ __launch_bounds__(256) void scan_phaseA(const int* __restrict__ deg,
        int* __restrict__ blocksum, int N) {
    __shared__ int red[256];
    int i0 = blockIdx.x * 512 + threadIdx.x * 2;
    int s = 0;
    if (i0 < N)     s += deg[i0];
    if (i0 + 1 < N) s += deg[i0 + 1];
    red[threadIdx.x] = s;
    __syncthreads();
    for (int off = 128; off; off >>= 1) {
        if (threadIdx.x < off) red[threadIdx.x] += red[threadIdx.x + off];
        __syncthreads();
    }
    if (threadIdx.x == 0) blocksum[blockIdx.x] = red[0];
}

// B: single block scans up to 1024 block sums (4 per thread), writes rowptr[N]=total
__global__ __launch_bounds__(256) void scan_phaseB(int* __restrict__ blocksum, int NB,
        int* __restrict__ rowptr, int N) {
    __shared__ int part[256];
    int t = threadIdx.x;
    int v[4]; int sum = 0;
    #pragma unroll
    for (int j = 0; j < 4; ++j) {
        int i = 4 * t + j;
        v[j] = (i < NB) ? blocksum[i] : 0;
        sum += v[j];
    }
    part[t] = sum;
    __syncthreads();
    for (int off = 1; off < 256; off <<= 1) {
        int u = (t >= off) ? part[t - off] : 0;
        __syncthreads();
        part[t] += u;
        __syncthreads();
    }
    int run = part[t] - sum;   // exclusive prefix
    #pragma unroll
    for (int j = 0; j < 4; ++j) {
        int i = 4 * t + j;
        if (i < NB) blocksum[i] = run;
        run += v[j];
    }
    if (t == 255) rowptr[N] = part[255];
}

// C: per-block local scan + offset -> rowptr/cursor
__global__ __launch_bounds__(256) void scan_phaseC(const int* __restrict__ deg,
        const int* __restrict__ blockoff, int* __restrict__ rowptr,
        int* __restrict__ cursor, int N) {
    __shared__ int part[256];
    int t = threadIdx.x;
    int i0 = blockIdx.x * 512 + 2 * t;
    int d0 = (i0 < N)     ? deg[i0]     : 0;
    int d1 = (i0 + 1 < N) ? deg[i0 + 1] : 0;
    int sum = d0 + d1;
    part[t] = sum;
    __syncthreads();
    for (int off = 1; off < 256; off <<= 1) {
        int u = (t >= off) ? part[t - off] : 0;
        __syncthreads();
        part[t] += u;
        __syncthreads();
    }
    int run = blockoff[blockIdx.x] + part[t] - sum;
    if (i0 < N)     { rowptr[i0] = run; cursor[i0] = run; }
    run += d0;
    if (i0 + 1 < N) { rowptr[i0 + 1] = run; cursor[i0 + 1] = run; }
}

__global__ void bucket_kernel(const int* __restrict__ src, const int* __restrict__ dst,
        int* __restrict__ cursor, int* __restrict__ ebuf, int E) {
    int e = blockIdx.x * blockDim.x + threadIdx.x;
    if (e < E) {
        int p = atomicAdd(&cursor[dst[e]], 1);
        ebuf[p] = src[e];
    }
}

// ------------------------------------------------------- weight pre-transpose
// Wt[fo*ldt + fi] = W[fi*cols + fo], output canonical bf16
__global__ void transpose_kernel(const void* __restrict__ W,
        __hip_bfloat16* __restrict__ Wt, int rows, int cols, int ldt,
        const int* __restrict__ flags) {
    int idx = blockIdx.x * blockDim.x + threadIdx.x;
    if (idx < rows * cols) {
        int fi = idx / cols, fo = idx % cols;
        Wt[fo * ldt + fi] = __float2bfloat16(loadf(W, idx, flags[1] != 0));
    }
}

// --------------------------------------------------------------- MFMA GEMM
static __device__ __forceinline__ bf16x8 load_frag(const void* X, size_t off, bool f32) {
    if (!f32) return *(const bf16x8*)((const __hip_bfloat16*)X + off);
    const float* p = (const float*)X + off;
    float4 a = *(const float4*)p;
    float4 b = *(const float4*)(p + 4);
    bf16x8 r;
    r[0] = f2bs(a.x); r[1] = f2bs(a.y); r[2] = f2bs(a.z); r[3] = f2bs(a.w);
    r[4] = f2bs(b.x); r[5] = f2bs(b.y); r[6] = f2bs(b.z); r[7] = f2bs(b.w);
    return r;
}

// out[node][fo] = sum_k X[node][k] * Wt[fo][k]  (+bias[fo]); out bf16 or f32 (out_f32).
// X split at K0 between X0/X1. One wave = 16-node stripe x all Ncols.
__global__ __launch_bounds__(256) void gemm_mfma(
        const void* __restrict__ X0, const void* __restrict__ X1, int K0, int K, int xflag,
        const __hip_bfloat16* __restrict__ Wt, const void* __restrict__ bias,
        void* __restrict__ outp, int ldo, int out_f32, int M, int Ncols,
        const int* __restrict__ flags) {
    bool pf = flags[1] != 0;       // raw float inputs are f32
    bool xf32 = (xflag != 0) && pf;
    int wave = (blockIdx.x * blockDim.x + threadIdx.x) >> 6;
    int node_base = wave << 4;
    if (node_base >= M) return;
    int lane = threadIdx.x & 63;
    int quad = lane >> 4;          // 0..3
    int r = lane & 15;             // 0..15
    int node = node_base + r;
    int nodeL = min(node, M - 1);  // clamp for loads
    int ksteps = K >> 5;           // K/32, max 8

    bf16x8 xf[8];
    #pragma unroll
    for (int ks = 0; ks < 8; ++ks) {
        if (ks >= ksteps) break;
        int k = ks * 32 + quad * 8;
        if (k < K0) xf[ks] = load_frag(X0, (size_t)nodeL * K0 + k, xf32);
        else        xf[ks] = load_frag(X1, (size_t)nodeL * (K - K0) + (k - K0), xf32);
    }

    int ntiles = Ncols >> 4;
    for (int ft = 0; ft < ntiles; ++ft) {
        f32x4 acc = {0.f, 0.f, 0.f, 0.f};
        const __hip_bfloat16* wrow = Wt + (size_t)(ft * 16 + r) * K + quad * 8;
        #pragma unroll
        for (int ks = 0; ks < 8; ++ks) {
            if (ks >= ksteps) break;
            bf16x8 wf = *(const bf16x8*)(wrow + ks * 32);
            acc = __builtin_amdgcn_mfma_f32_16x16x32_bf16(wf, xf[ks], acc, 0, 0, 0);
        }
        // D layout: col = lane&15 -> node r, row = quad*4 + reg -> fo
        int fo = ft * 16 + quad * 4;
        float b0 = 0.f, b1 = 0.f, b2 = 0.f, b3 = 0.f;
        if (bias) {
            b0 = loadf(bias, fo + 0, pf); b1 = loadf(bias, fo + 1, pf);
            b2 = loadf(bias, fo + 2, pf); b3 = loadf(bias, fo + 3, pf);
        }
        if (node < M) {
            if (out_f32) {
                float4 res;
                res.x = acc[0] + b0; res.y = acc[1] + b1;
                res.z = acc[2] + b2; res.w = acc[3] + b3;
                *(float4*)((float*)outp + (size_t)node * ldo + fo) = res;
            } else {
                short4 res;
                res.x = f2bs(acc[0] + b0); res.y = f2bs(acc[1] + b1);
                res.z = f2bs(acc[2] + b2); res.w = f2bs(acc[3] + b3);
                *(short4*)((short*)outp + (size_t)node * ldo + fo) = res;
            }
        }
    }
}

// --------------------------------------- fused mean-agg + bias + lin_r + LN + ReLU
// yz bf16 [N][256]: cols 0..127 = y (projected neighbor feats), 128..255 = z (lin_r)
// One wave per node; lane handles features 2*lane, 2*lane+1. f32 accumulation.
__global__ __launch_bounds__(256) void agg_ln_relu(
        const __hip_bfloat16* __restrict__ yz, const int* __restrict__ rowptr,
        const int* __restrict__ ebuf,
        const void* __restrict__ bn, const void* __restrict__ g,
        const void* __restrict__ be, __hip_bfloat16* __restrict__ hout, int N,
        const int* __restrict__ flags) {
    int node = (blockIdx.x * blockDim.x + threadIdx.x) >> 6;
    if (node >= N) return;
    bool pf = flags[1] != 0;
    int lane = threadIdx.x & 63;
    int f = lane * 2;
    const short* yzs = (const short*)yz;
    int start = rowptr[node], end = rowptr[node + 1];
    float a0 = 0.f, a1 = 0.f;
    for (int i = start; i < end; ++i) {
        int s = ebuf[i];                          // wave-uniform load
        short2 t = *(const short2*)(yzs + (size_t)s * 256 + f);
        a0 += bs2f(t.x); a1 += bs2f(t.y);
    }
    float inv = 1.f / fmaxf((float)(end - start), 1.f);
    short2 zt = *(const short2*)(yzs + (size_t)node * 256 + 128 + f);
    float v0 = a0 * inv + loadf(bn, f, pf)     + bs2f(zt.x);
    float v1 = a1 * inv + loadf(bn, f + 1, pf) + bs2f(zt.y);
    float s = v0 + v1;
    #pragma unroll
    for (int off = 32; off > 0; off >>= 1) s += __shfl_xor(s, off, 64);
    float mu = s * (1.f / 128.f);
    float d0 = v0 - mu, d1 = v1 - mu;
    float q = d0 * d0 + d1 * d1;
    #pragma unroll
    for (int off = 32; off > 0; off >>= 1) q += __shfl_xor(q, off, 64);
    float rstd = rsqrtf(q * (1.f / 128.f) + 1e-5f);
    float o0 = fmaxf(d0 * rstd * loadf(g, f, pf)     + loadf(be, f, pf),     0.f);
    float o1 = fmaxf(d1 * rstd * loadf(g, f + 1, pf) + loadf(be, f + 1, pf), 0.f);
    short* hp = (short*)hout + (size_t)node * 128 + f;
    hp[0] = f2bs(o0);
    hp[1] = f2bs(o1);
}

// ------------------------------------------------------------- MLP head
// out = relu(feats @ Wh1 + bh1) @ Wh2 + bh2, feats f32 [N][128]
// output dtype follows flags[1]: f32 if inputs f32, else bf16
__global__ __launch_bounds__(256) void head_kernel(
        const float* __restrict__ feats, const void* __restrict__ Wh1,
        const void* __restrict__ bh1, const void* __restrict__ Wh2,
        const void* __restrict__ bh2, void* __restrict__ outp, int N,
        const int* __restrict__ flags) {
    __shared__ float sfe[8 * 128];
    __shared__ float shid[8 * 32];
    bool pf = flags[1] != 0;
    int nb = blockIdx.x * 8;
    int tid = threadIdx.x;
    {
        int i = tid * 4;
        int gnode = nb + (i >> 7);
        float4 v = make_float4(0.f, 0.f, 0.f, 0.f);
        if (gnode < N) v = *(const float4*)(feats + (size_t)gnode * 128 + (i & 127));
        *(float4*)(sfe + i) = v;
    }
    __syncthreads();
    {
        int nloc = tid >> 5, col = tid & 31;
        float acc = loadf(bh1, col, pf);
        const float* fr = sfe + nloc * 128;
        #pragma unroll 8
        for (int k = 0; k < 128; ++k) acc += fr[k] * loadf(Wh1, k * 32 + col, pf);
        shid[nloc * 32 + col] = fmaxf(acc, 0.f);
    }
    __syncthreads();
    if (tid < 128) {
        int nloc = tid >> 4, col = tid & 15;
        int gnode = nb + nloc;
        if (gnode < N) {
            float acc = loadf(bh2, col, pf);
            const float* hr = shid + nloc * 32;
            #pragma unroll
            for (int k = 0; k < 32; ++k) acc += hr[k] * loadf(Wh2, k * 16 + col, pf);
            if (pf) ((float*)outp)[(size_t)gnode * 16 + col] = acc;
            else    ((__hip_bfloat16*)outp)[(size_t)gnode * 16 + col] = __float2bfloat16(acc);
        }
    }
}

// ---------------------------------------------------------------- launcher
extern "C" void kernel_launch(void* const* d_in, const int* in_sizes, int n_in,
                              void* d_out, int out_size, void* d_ws, size_t ws_size,
                              hipStream_t stream) {
    const void* x    = d_in[0];
    const unsigned* ei = (const unsigned*)d_in[1];
    const void* Wnl0 = d_in[2];
    const void* bnl0 = d_in[3];
    const void* Wr0  = d_in[4];
    const void* Wnl1 = d_in[5];
    const void* bnl1 = d_in[6];
    const void* Wr1  = d_in[7];
    const void* g0   = d_in[8];
    const void* be0  = d_in[9];
    const void* g1   = d_in[10];
    const void* be1  = d_in[11];
    const void* Wjk  = d_in[12];
    const void* bjk  = d_in[13];
    const void* Wh1  = d_in[14];
    const void* bh1  = d_in[15];
    const void* Wh2  = d_in[16];
    const void* bh2  = d_in[17];

    const int N = in_sizes[0] / 256;
    const int E = in_sizes[1] / 2;

    char* ws = (char*)d_ws;
    size_t off = 0;
    auto alloc = [&](size_t bytes) -> void* {
        void* p = ws + off;
        off = (off + bytes + 255) & ~(size_t)255;
        return p;
    };
    int* flags  = (int*)alloc(256);
    int* src    = (int*)alloc((size_t)E * 4);
    int* dst    = (int*)alloc((size_t)E * 4);
    int* rowptr = (int*)alloc((size_t)(N + 1) * 4);
    int* deg    = (int*)alloc((size_t)N * 4);
    int* cursor = (int*)alloc((size_t)N * 4);
    int* ebuf   = (int*)alloc((size_t)E * 4);
    int* blocksum = (int*)alloc(1024 * 4);
    __hip_bfloat16* Wt0  = (__hip_bfloat16*)alloc(256 * 256 * 2);
    __hip_bfloat16* Wt1  = (__hip_bfloat16*)alloc(256 * 128 * 2);
    __hip_bfloat16* Wtjk = (__hip_bfloat16*)alloc(128 * 256 * 2);
    __hip_bfloat16* yz = (__hip_bfloat16*)alloc((size_t)N * 256 * 2);   // also feats f32 [N][128]
    __hip_bfloat16* h0 = (__hip_bfloat16*)alloc((size_t)N * 128 * 2);
    __hip_bfloat16* h1 = (__hip_bfloat16*)alloc((size_t)N * 128 * 2);
    float* feats = (float*)yz;   // yz dead after second agg; same byte size

    // dtype detection + canonical edge decode
    detect_kernel<<<1, 256, 0, stream>>>(ei, (const unsigned short*)x, flags);
    int eb = (E + 255) / 256;
    decode_edges<<<eb, 256, 0, stream>>>(ei, E, flags, src, dst);

    // CSR build (multi-block 3-phase scan; 512 elements per block)
    (void)hipMemsetAsync(deg, 0, (size_t)N * 4, stream);
    deg_kernel<<<eb, 256, 0, stream>>>(dst, deg, E);
    int NB = (N + 511) / 512;
    scan_phaseA<<<NB, 256, 0, stream>>>(deg, blocksum, N);
    scan_phaseB<<<1, 256, 0, stream>>>(blocksum, NB, rowptr, N);
    scan_phaseC<<<NB, 256, 0, stream>>>(deg, blocksum, rowptr, cursor, N);
    bucket_kernel<<<eb, 256, 0, stream>>>(src, dst, cursor, ebuf, E);

    // Weight transposes: Wt0 = [Wnl0^T ; Wr0^T] (256 rows x K=256),
    // Wt1 = [Wnl1^T ; Wr1^T] (256 rows x K=128), Wtjk = Wjk^T (128 rows x K=256)
    transpose_kernel<<<(256 * 128 + 255) / 256, 256, 0, stream>>>(Wnl0, Wt0, 256, 128, 256, flags);
    transpose_kernel<<<(256 * 128 + 255) / 256, 256, 0, stream>>>(Wr0,  Wt0 + 128 * 256, 256, 128, 256, flags);
    transpose_kernel<<<(128 * 128 + 255) / 256, 256, 0, stream>>>(Wnl1, Wt1, 128, 128, 128, flags);
    transpose_kernel<<<(128 * 128 + 255) / 256, 256, 0, stream>>>(Wr1,  Wt1 + 128 * 128, 128, 128, 128, flags);
    transpose_kernel<<<(256 * 128 + 255) / 256, 256, 0, stream>>>(Wjk,  Wtjk, 256, 128, 256, flags);

    int gwaves = (N + 15) / 16;
    int gblocks = (gwaves * 64 + 255) / 256;
    int ablocks = (int)(((size_t)N * 64 + 255) / 256);

    // layer 0: project (y0 = x@Wnl0, z0 = x@Wr0) -> agg+LN+ReLU -> h0
    gemm_mfma<<<gblocks, 256, 0, stream>>>(x, x, 256, 256, 1, Wt0, nullptr, yz, 256, 0, N, 256, flags);
    agg_ln_relu<<<ablocks, 256, 0, stream>>>(yz, rowptr, ebuf, bnl0, g0, be0, h0, N, flags);

    // layer 1
    gemm_mfma<<<gblocks, 256, 0, stream>>>(h0, h0, 128, 128, 0, Wt1, nullptr, yz, 256, 0, N, 256, flags);
    agg_ln_relu<<<ablocks, 256, 0, stream>>>(yz, rowptr, ebuf, bnl1, g1, be1, h1, N, flags);

    // JK: feats = [h0|h1] @ Wjk + bjk   (K split 128/128), f32 output
    gemm_mfma<<<gblocks, 256, 0, stream>>>(h0, h1, 128, 256, 0, Wtjk, bjk, feats, 128, 1, N, 128, flags);

    // MLP head (output dtype follows detected float dtype)
    head_kernel<<<(N + 7) / 8, 256, 0, stream>>>(feats, Wh1, bh1, Wh2, bh2, d_out, N, flags);
}

// Round 5
// 841.616 us; speedup vs baseline: 1.4794x; 1.2221x over previous
//
#include <hip/hip_runtime.h>
#include <hip/hip_bf16.h>

typedef __attribute__((ext_vector_type(8))) short bf16x8;   // 8 bf16 = 4 VGPRs
typedef __attribute__((ext_vector_type(4))) float f32x4;    // 4 f32 acc

static __device__ __forceinline__ float bf2f(__hip_bfloat16 v) { return __bfloat162float(v); }

static __device__ __forceinline__ float bs2f(short s) {
    unsigned u = ((unsigned)(unsigned short)s) << 16;
    float f; __builtin_memcpy(&f, &u, 4); return f;
}
static __device__ __forceinline__ short f2bs(float v) {
    __hip_bfloat16 b = __float2bfloat16(v);
    short s; __builtin_memcpy(&s, &b, 2); return s;
}
// read element i of a float array that is either f32 or bf16
static __device__ __forceinline__ float loadf(const void* p, int i, bool f32) {
    if (f32) return ((const float*)p)[i];
    return bf2f(((const __hip_bfloat16*)p)[i]);
}

// ------------------------------------------------- runtime dtype detection
// flags[0] = 1 if edge_index is int64 (odd 32-bit words of first 2048 pairs all 0)
// flags[1] = 1 if float inputs are f32 (bf16 view of x has huge-exponent lanes)
__global__ __launch_bounds__(256) void detect_kernel(const unsigned* __restrict__ ew,
        const unsigned short* __restrict__ xw, int* __restrict__ flags) {
    __shared__ int s_odd, s_f32;
    int t = threadIdx.x;
    if (t == 0) { s_odd = 0; s_f32 = 0; }
    __syncthreads();
    unsigned acc = 0;
    for (int i = t; i < 2048; i += 256) acc |= ew[2 * i + 1];
    if (acc) atomicOr(&s_odd, 1);
    int f32ev = 0;
    for (int i = t; i < 4096; i += 256) {
        unsigned e = (xw[i] >> 7) & 0xFF;          // bf16 exponent field
        if (e >= 0xC0) f32ev = 1;                  // impossible for real bf16 data
    }
    if (f32ev) atomicOr(&s_f32, 1);
    __syncthreads();
    if (t == 0) { flags[0] = s_odd ? 0 : 1; flags[1] = s_f32; }
}

// decode edge_index (int32 or int64 layout) into canonical int32 src/dst
__global__ void decode_edges(const unsigned* __restrict__ ew, int E,
        const int* __restrict__ flags, int* __restrict__ src, int* __restrict__ dst) {
    int e = blockIdx.x * blockDim.x + threadIdx.x;
    if (e >= E) return;
    if (flags[0]) {      // int64: words [2e] lo; dst row starts at word 2E
        src[e] = (int)ew[2 * (size_t)e];
        dst[e] = (int)ew[2 * (size_t)E + 2 * (size_t)e];
    } else {
        src[e] = (int)ew[e];
        dst[e] = (int)ew[(size_t)E + e];
    }
}

// ---------------------------------------------------------------- CSR build
__global__ void deg_kernel(const int* __restrict__ dst, int* __restrict__ deg, int E) {
    int e = blockIdx.x * blockDim.x + threadIdx.x;
    if (e < E) atomicAdd(&deg[dst[e]], 1);
}

// ---- 3-phase multi-block exclusive scan (512 elements per block) ----
// A: per-block sum
__global__ __launch_bounds__(256) void scan_phaseA(const int* __restrict__ deg,
        int* __restrict__ blocksum, int N) {
    __shared__ int red[256];
    int i0 = blockIdx.x * 512 + threadIdx.x * 2;
    int s = 0;
    if (i0 < N)     s += deg[i0];
    if (i0 + 1 < N) s += deg[i0 + 1];
    red[threadIdx.x] = s;
    __syncthreads();
    for (int off = 128; off; off >>= 1) {
        if (threadIdx.x < off) red[threadIdx.x] += red[threadIdx.x + off];
        __syncthreads();
    }
    if (threadIdx.x == 0) blocksum[blockIdx.x] = red[0];
}

// B: single block scans up to 1024 block sums (4 per thread), writes rowptr[N]=total
__global__ __launch_bounds__(256) void scan_phaseB(int* __restrict__ blocksum, int NB,
        int* __restrict__ rowptr, int N) {
    __shared__ int part[256];
    int t = threadIdx.x;
    int v[4]; int sum = 0;
    #pragma unroll
    for (int j = 0; j < 4; ++j) {
        int i = 4 * t + j;
        v[j] = (i < NB) ? blocksum[i] : 0;
        sum += v[j];
    }
    part[t] = sum;
    __syncthreads();
    for (int off = 1; off < 256; off <<= 1) {
        int u = (t >= off) ? part[t - off] : 0;
        __syncthreads();
        part[t] += u;
        __syncthreads();
    }
    int run = part[t] - sum;   // exclusive prefix
    #pragma unroll
    for (int j = 0; j < 4; ++j) {
        int i = 4 * t + j;
        if (i < NB) blocksum[i] = run;
        run += v[j];
    }
    if (t == 255) rowptr[N] = part[255];
}

// C: per-block local scan + offset -> rowptr/cursor
__global__ __launch_bounds__(256) void scan_phaseC(const int* __restrict__ deg,
        const int* __restrict__ blockoff, int* __restrict__ rowptr,
        int* __restrict__ cursor, int N) {
    __shared__ int part[256];
    int t = threadIdx.x;
    int i0 = blockIdx.x * 512 + 2 * t;
    int d0 = (i0 < N)     ? deg[i0]     : 0;
    int d1 = (i0 + 1 < N) ? deg[i0 + 1] : 0;
    int sum = d0 + d1;
    part[t] = sum;
    __syncthreads();
    for (int off = 1; off < 256; off <<= 1) {
        int u = (t >= off) ? part[t - off] : 0;
        __syncthreads();
        part[t] += u;
        __syncthreads();
    }
    int run = blockoff[blockIdx.x] + part[t] - sum;
    if (i0 < N)     { rowptr[i0] = run; cursor[i0] = run; }
    run += d0;
    if (i0 + 1 < N) { rowptr[i0 + 1] = run; cursor[i0 + 1] = run; }
}

__global__ void bucket_kernel(const int* __restrict__ src, const int* __restrict__ dst,
        int* __restrict__ cursor, int* __restrict__ ebuf, int E) {
    int e = blockIdx.x * blockDim.x + threadIdx.x;
    if (e < E) {
        int p = atomicAdd(&cursor[dst[e]], 1);
        ebuf[p] = src[e];
    }
}

// ------------------------------------------------------- weight pre-transpose
// Wt[fo*ldt + fi] = W[fi*cols + fo], output canonical bf16
__global__ void transpose_kernel(const void* __restrict__ W,
        __hip_bfloat16* __restrict__ Wt, int rows, int cols, int ldt,
        const int* __restrict__ flags) {
    int idx = blockIdx.x * blockDim.x + threadIdx.x;
    if (idx < rows * cols) {
        int fi = idx / cols, fo = idx % cols;
        Wt[fo * ldt + fi] = __float2bfloat16(loadf(W, idx, flags[1] != 0));
    }
}

// --------------------------------------------------------------- MFMA GEMM
static __device__ __forceinline__ bf16x8 load_frag(const void* X, size_t off, bool f32) {
    if (!f32) return *(const bf16x8*)((const __hip_bfloat16*)X + off);
    const float* p = (const float*)X + off;
    float4 a = *(const float4*)p;
    float4 b = *(const float4*)(p + 4);
    bf16x8 r;
    r[0] = f2bs(a.x); r[1] = f2bs(a.y); r[2] = f2bs(a.z); r[3] = f2bs(a.w);
    r[4] = f2bs(b.x); r[5] = f2bs(b.y); r[6] = f2bs(b.z); r[7] = f2bs(b.w);
    return r;
}

// out[node][fo] = sum_k X[node][k] * Wt[fo][k]  (+bias[fo]); out bf16 or f32 (out_f32).
// X split at K0 between X0/X1. One wave = 16-node stripe x all Ncols.
__global__ __launch_bounds__(256) void gemm_mfma(
        const void* __restrict__ X0, const void* __restrict__ X1, int K0, int K, int xflag,
        const __hip_bfloat16* __restrict__ Wt, const void* __restrict__ bias,
        void* __restrict__ outp, int ldo, int out_f32, int M, int Ncols,
        const int* __restrict__ flags) {
    bool pf = flags[1] != 0;       // raw float inputs are f32
    bool xf32 = (xflag != 0) && pf;
    int wave = (blockIdx.x * blockDim.x + threadIdx.x) >> 6;
    int node_base = wave << 4;
    if (node_base >= M) return;
    int lane = threadIdx.x & 63;
    int quad = lane >> 4;          // 0..3
    int r = lane & 15;             // 0..15
    int node = node_base + r;
    int nodeL = min(node, M - 1);  // clamp for loads
    int ksteps = K >> 5;           // K/32, max 8

    bf16x8 xf[8];
    #pragma unroll
    for (int ks = 0; ks < 8; ++ks) {
        if (ks >= ksteps) break;
        int k = ks * 32 + quad * 8;
        if (k < K0) xf[ks] = load_frag(X0, (size_t)nodeL * K0 + k, xf32);
        else        xf[ks] = load_frag(X1, (size_t)nodeL * (K - K0) + (k - K0), xf32);
    }

    int ntiles = Ncols >> 4;
    for (int ft = 0; ft < ntiles; ++ft) {
        f32x4 acc = {0.f, 0.f, 0.f, 0.f};
        const __hip_bfloat16* wrow = Wt + (size_t)(ft * 16 + r) * K + quad * 8;
        #pragma unroll
        for (int ks = 0; ks < 8; ++ks) {
            if (ks >= ksteps) break;
            bf16x8 wf = *(const bf16x8*)(wrow + ks * 32);
            acc = __builtin_amdgcn_mfma_f32_16x16x32_bf16(wf, xf[ks], acc, 0, 0, 0);
        }
        // D layout: col = lane&15 -> node r, row = quad*4 + reg -> fo
        int fo = ft * 16 + quad * 4;
        float b0 = 0.f, b1 = 0.f, b2 = 0.f, b3 = 0.f;
        if (bias) {
            b0 = loadf(bias, fo + 0, pf); b1 = loadf(bias, fo + 1, pf);
            b2 = loadf(bias, fo + 2, pf); b3 = loadf(bias, fo + 3, pf);
        }
        if (node < M) {
            if (out_f32) {
                float4 res;
                res.x = acc[0] + b0; res.y = acc[1] + b1;
                res.z = acc[2] + b2; res.w = acc[3] + b3;
                *(float4*)((float*)outp + (size_t)node * ldo + fo) = res;
            } else {
                short4 res;
                res.x = f2bs(acc[0] + b0); res.y = f2bs(acc[1] + b1);
                res.z = f2bs(acc[2] + b2); res.w = f2bs(acc[3] + b3);
                *(short4*)((short*)outp + (size_t)node * ldo + fo) = res;
            }
        }
    }
}

// --------------------------------------- fused mean-agg + bias + lin_r + LN + ReLU
// yz bf16 [N][256]: cols 0..127 = y (projected neighbor feats), 128..255 = z (lin_r)
// One wave per node; lane handles features 2*lane, 2*lane+1. f32 accumulation.
// Neighbor loop is 8-way batched: 8 independent gathers in flight per wave
// (breaks the load->use serial chain that limited R4 to 1 outstanding load).
__global__ __launch_bounds__(256) void agg_ln_relu(
        const __hip_bfloat16* __restrict__ yz, const int* __restrict__ rowptr,
        const int* __restrict__ ebuf,
        const void* __restrict__ bn, const void* __restrict__ g,
        const void* __restrict__ be, __hip_bfloat16* __restrict__ hout, int N,
        const int* __restrict__ flags) {
    int node = (blockIdx.x * blockDim.x + threadIdx.x) >> 6;
    if (node >= N) return;
    node = __builtin_amdgcn_readfirstlane(node);   // provably wave-uniform -> s_loads
    bool pf = flags[1] != 0;
    int lane = threadIdx.x & 63;
    int f = lane * 2;
    const short* yzs = (const short*)yz;
    int start = rowptr[node], end = rowptr[node + 1];
    float a0 = 0.f, a1 = 0.f;
    int i = start;
    for (; i + 8 <= end; i += 8) {
        int n0 = ebuf[i + 0], n1 = ebuf[i + 1], n2 = ebuf[i + 2], n3 = ebuf[i + 3];
        int n4 = ebuf[i + 4], n5 = ebuf[i + 5], n6 = ebuf[i + 6], n7 = ebuf[i + 7];
        short2 t0 = *(const short2*)(yzs + (size_t)n0 * 256 + f);
        short2 t1 = *(const short2*)(yzs + (size_t)n1 * 256 + f);
        short2 t2 = *(const short2*)(yzs + (size_t)n2 * 256 + f);
        short2 t3 = *(const short2*)(yzs + (size_t)n3 * 256 + f);
        short2 t4 = *(const short2*)(yzs + (size_t)n4 * 256 + f);
        short2 t5 = *(const short2*)(yzs + (size_t)n5 * 256 + f);
        short2 t6 = *(const short2*)(yzs + (size_t)n6 * 256 + f);
        short2 t7 = *(const short2*)(yzs + (size_t)n7 * 256 + f);
        a0 += bs2f(t0.x) + bs2f(t1.x) + bs2f(t2.x) + bs2f(t3.x)
            + bs2f(t4.x) + bs2f(t5.x) + bs2f(t6.x) + bs2f(t7.x);
        a1 += bs2f(t0.y) + bs2f(t1.y) + bs2f(t2.y) + bs2f(t3.y)
            + bs2f(t4.y) + bs2f(t5.y) + bs2f(t6.y) + bs2f(t7.y);
    }
    for (; i + 2 <= end; i += 2) {
        int n0 = ebuf[i + 0], n1 = ebuf[i + 1];
        short2 t0 = *(const short2*)(yzs + (size_t)n0 * 256 + f);
        short2 t1 = *(const short2*)(yzs + (size_t)n1 * 256 + f);
        a0 += bs2f(t0.x) + bs2f(t1.x);
        a1 += bs2f(t0.y) + bs2f(t1.y);
    }
    if (i < end) {
        int n0 = ebuf[i];
        short2 t0 = *(const short2*)(yzs + (size_t)n0 * 256 + f);
        a0 += bs2f(t0.x);
        a1 += bs2f(t0.y);
    }
    float inv = 1.f / fmaxf((float)(end - start), 1.f);
    short2 zt = *(const short2*)(yzs + (size_t)node * 256 + 128 + f);
    float v0 = a0 * inv + loadf(bn, f, pf)     + bs2f(zt.x);
    float v1 = a1 * inv + loadf(bn, f + 1, pf) + bs2f(zt.y);
    float s = v0 + v1;
    #pragma unroll
    for (int off = 32; off > 0; off >>= 1) s += __shfl_xor(s, off, 64);
    float mu = s * (1.f / 128.f);
    float d0 = v0 - mu, d1 = v1 - mu;
    float q = d0 * d0 + d1 * d1;
    #pragma unroll
    for (int off = 32; off > 0; off >>= 1) q += __shfl_xor(q, off, 64);
    float rstd = rsqrtf(q * (1.f / 128.f) + 1e-5f);
    float o0 = fmaxf(d0 * rstd * loadf(g, f, pf)     + loadf(be, f, pf),     0.f);
    float o1 = fmaxf(d1 * rstd * loadf(g, f + 1, pf) + loadf(be, f + 1, pf), 0.f);
    short* hp = (short*)hout + (size_t)node * 128 + f;
    hp[0] = f2bs(o0);
    hp[1] = f2bs(o1);
}

// ------------------------------------------------------------- MLP head
// out = relu(feats @ Wh1 + bh1) @ Wh2 + bh2, feats f32 [N][128]
// output dtype follows flags[1]: f32 if inputs f32, else bf16
__global__ __launch_bounds__(256) void head_kernel(
        const float* __restrict__ feats, const void* __restrict__ Wh1,
        const void* __restrict__ bh1, const void* __restrict__ Wh2,
        const void* __restrict__ bh2, void* __restrict__ outp, int N,
        const int* __restrict__ flags) {
    __shared__ float sfe[8 * 128];
    __shared__ float shid[8 * 32];
    bool pf = flags[1] != 0;
    int nb = blockIdx.x * 8;
    int tid = threadIdx.x;
    {
        int i = tid * 4;
        int gnode = nb + (i >> 7);
        float4 v = make_float4(0.f, 0.f, 0.f, 0.f);
        if (gnode < N) v = *(const float4*)(feats + (size_t)gnode * 128 + (i & 127));
        *(float4*)(sfe + i) = v;
    }
    __syncthreads();
    {
        int nloc = tid >> 5, col = tid & 31;
        float acc = loadf(bh1, col, pf);
        const float* fr = sfe + nloc * 128;
        #pragma unroll 8
        for (int k = 0; k < 128; ++k) acc += fr[k] * loadf(Wh1, k * 32 + col, pf);
        shid[nloc * 32 + col] = fmaxf(acc, 0.f);
    }
    __syncthreads();
    if (tid < 128) {
        int nloc = tid >> 4, col = tid & 15;
        int gnode = nb + nloc;
        if (gnode < N) {
            float acc = loadf(bh2, col, pf);
            const float* hr = shid + nloc * 32;
            #pragma unroll
            for (int k = 0; k < 32; ++k) acc += hr[k] * loadf(Wh2, k * 16 + col, pf);
            if (pf) ((float*)outp)[(size_t)gnode * 16 + col] = acc;
            else    ((__hip_bfloat16*)outp)[(size_t)gnode * 16 + col] = __float2bfloat16(acc);
        }
    }
}

// ---------------------------------------------------------------- launcher
extern "C" void kernel_launch(void* const* d_in, const int* in_sizes, int n_in,
                              void* d_out, int out_size, void* d_ws, size_t ws_size,
                              hipStream_t stream) {
    const void* x    = d_in[0];
    const unsigned* ei = (const unsigned*)d_in[1];
    const void* Wnl0 = d_in[2];
    const void* bnl0 = d_in[3];
    const void* Wr0  = d_in[4];
    const void* Wnl1 = d_in[5];
    const void* bnl1 = d_in[6];
    const void* Wr1  = d_in[7];
    const void* g0   = d_in[8];
    const void* be0  = d_in[9];
    const void* g1   = d_in[10];
    const void* be1  = d_in[11];
    const void* Wjk  = d_in[12];
    const void* bjk  = d_in[13];
    const void* Wh1  = d_in[14];
    const void* bh1  = d_in[15];
    const void* Wh2  = d_in[16];
    const void* bh2  = d_in[17];

    const int N = in_sizes[0] / 256;
    const int E = in_sizes[1] / 2;

    char* ws = (char*)d_ws;
    size_t off = 0;
    auto alloc = [&](size_t bytes) -> void* {
        void* p = ws + off;
        off = (off + bytes + 255) & ~(size_t)255;
        return p;
    };
    int* flags  = (int*)alloc(256);
    int* src    = (int*)alloc((size_t)E * 4);
    int* dst    = (int*)alloc((size_t)E * 4);
    int* rowptr = (int*)alloc((size_t)(N + 1) * 4);
    int* deg    = (int*)alloc((size_t)N * 4);
    int* cursor = (int*)alloc((size_t)N * 4);
    int* ebuf   = (int*)alloc((size_t)E * 4);
    int* blocksum = (int*)alloc(1024 * 4);
    __hip_bfloat16* Wt0  = (__hip_bfloat16*)alloc(256 * 256 * 2);
    __hip_bfloat16* Wt1  = (__hip_bfloat16*)alloc(256 * 128 * 2);
    __hip_bfloat16* Wtjk = (__hip_bfloat16*)alloc(128 * 256 * 2);
    __hip_bfloat16* yz = (__hip_bfloat16*)alloc((size_t)N * 256 * 2);   // also feats f32 [N][128]
    __hip_bfloat16* h0 = (__hip_bfloat16*)alloc((size_t)N * 128 * 2);
    __hip_bfloat16* h1 = (__hip_bfloat16*)alloc((size_t)N * 128 * 2);
    float* feats = (float*)yz;   // yz dead after second agg; same byte size

    // dtype detection + canonical edge decode
    detect_kernel<<<1, 256, 0, stream>>>(ei, (const unsigned short*)x, flags);
    int eb = (E + 255) / 256;
    decode_edges<<<eb, 256, 0, stream>>>(ei, E, flags, src, dst);

    // CSR build (multi-block 3-phase scan; 512 elements per block)
    (void)hipMemsetAsync(deg, 0, (size_t)N * 4, stream);
    deg_kernel<<<eb, 256, 0, stream>>>(dst, deg, E);
    int NB = (N + 511) / 512;
    scan_phaseA<<<NB, 256, 0, stream>>>(deg, blocksum, N);
    scan_phaseB<<<1, 256, 0, stream>>>(blocksum, NB, rowptr, N);
    scan_phaseC<<<NB, 256, 0, stream>>>(deg, blocksum, rowptr, cursor, N);
    bucket_kernel<<<eb, 256, 0, stream>>>(src, dst, cursor, ebuf, E);

    // Weight transposes: Wt0 = [Wnl0^T ; Wr0^T] (256 rows x K=256),
    // Wt1 = [Wnl1^T ; Wr1^T] (256 rows x K=128), Wtjk = Wjk^T (128 rows x K=256)
    transpose_kernel<<<(256 * 128 + 255) / 256, 256, 0, stream>>>(Wnl0, Wt0, 256, 128, 256, flags);
    transpose_kernel<<<(256 * 128 + 255) / 256, 256, 0, stream>>>(Wr0,  Wt0 + 128 * 256, 256, 128, 256, flags);
    transpose_kernel<<<(128 * 128 + 255) / 256, 256, 0, stream>>>(Wnl1, Wt1, 128, 128, 128, flags);
    transpose_kernel<<<(128 * 128 + 255) / 256, 256, 0, stream>>>(Wr1,  Wt1 + 128 * 128, 128, 128, 128, flags);
    transpose_kernel<<<(256 * 128 + 255) / 256, 256, 0, stream>>>(Wjk,  Wtjk, 256, 128, 256, flags);

    int gwaves = (N + 15) / 16;
    int gblocks = (gwaves * 64 + 255) / 256;
    int ablocks = (int)(((size_t)N * 64 + 255) / 256);

    // layer 0: project (y0 = x@Wnl0, z0 = x@Wr0) -> agg+LN+ReLU -> h0
    gemm_mfma<<<gblocks, 256, 0, stream>>>(x, x, 256, 256, 1, Wt0, nullptr, yz, 256, 0, N, 256, flags);
    agg_ln_relu<<<ablocks, 256, 0, stream>>>(yz, rowptr, ebuf, bnl0, g0, be0, h0, N, flags);

    // layer 1
    gemm_mfma<<<gblocks, 256, 0, stream>>>(h0, h0, 128, 128, 0, Wt1, nullptr, yz, 256, 0, N, 256, flags);
    agg_ln_relu<<<ablocks, 256, 0, stream>>>(yz, rowptr, ebuf, bnl1, g1, be1, h1, N, flags);

    // JK: feats = [h0|h1] @ Wjk + bjk   (K split 128/128), f32 output
    gemm_mfma<<<gblocks, 256, 0, stream>>>(h0, h1, 128, 256, 0, Wtjk, bjk, feats, 128, 1, N, 128, flags);

    // MLP head (output dtype follows detected float dtype)
    head_kernel<<<(N + 7) / 8, 256, 0, stream>>>(feats, Wh1, bh1, Wh2, bh2, d_out, N, flags);
}

// Round 6
// 839.125 us; speedup vs baseline: 1.4838x; 1.0030x over previous
//
#include <hip/hip_runtime.h>
#include <hip/hip_bf16.h>

typedef __attribute__((ext_vector_type(8))) short bf16x8;   // 8 bf16 = 4 VGPRs
typedef __attribute__((ext_vector_type(4))) float f32x4;    // 4 f32 acc

static __device__ __forceinline__ float bf2f(__hip_bfloat16 v) { return __bfloat162float(v); }

static __device__ __forceinline__ float bs2f(short s) {
    unsigned u = ((unsigned)(unsigned short)s) << 16;
    float f; __builtin_memcpy(&f, &u, 4); return f;
}
static __device__ __forceinline__ short f2bs(float v) {
    __hip_bfloat16 b = __float2bfloat16(v);
    short s; __builtin_memcpy(&s, &b, 2); return s;
}
// read element i of a float array that is either f32 or bf16
static __device__ __forceinline__ float loadf(const void* p, int i, bool f32) {
    if (f32) return ((const float*)p)[i];
    return bf2f(((const __hip_bfloat16*)p)[i]);
}

// ------------------------------------------------- runtime dtype detection
// flags[0] = 1 if edge_index is int64 (odd 32-bit words of first 2048 pairs all 0)
// flags[1] = 1 if float inputs are f32 (bf16 view of x has huge-exponent lanes)
__global__ __launch_bounds__(256) void detect_kernel(const unsigned* __restrict__ ew,
        const unsigned short* __restrict__ xw, int* __restrict__ flags) {
    __shared__ int s_odd, s_f32;
    int t = threadIdx.x;
    if (t == 0) { s_odd = 0; s_f32 = 0; }
    __syncthreads();
    unsigned acc = 0;
    for (int i = t; i < 2048; i += 256) acc |= ew[2 * i + 1];
    if (acc) atomicOr(&s_odd, 1);
    int f32ev = 0;
    for (int i = t; i < 4096; i += 256) {
        unsigned e = (xw[i] >> 7) & 0xFF;          // bf16 exponent field
        if (e >= 0xC0) f32ev = 1;                  // impossible for real bf16 data
    }
    if (f32ev) atomicOr(&s_f32, 1);
    __syncthreads();
    if (t == 0) { flags[0] = s_odd ? 0 : 1; flags[1] = s_f32; }
}

// decode edge_index (int32 or int64 layout) into canonical int32 src/dst
__global__ void decode_edges(const unsigned* __restrict__ ew, int E,
        const int* __restrict__ flags, int* __restrict__ src, int* __restrict__ dst) {
    int e = blockIdx.x * blockDim.x + threadIdx.x;
    if (e >= E) return;
    if (flags[0]) {      // int64: words [2e] lo; dst row starts at word 2E
        src[e] = (int)ew[2 * (size_t)e];
        dst[e] = (int)ew[2 * (size_t)E + 2 * (size_t)e];
    } else {
        src[e] = (int)ew[e];
        dst[e] = (int)ew[(size_t)E + e];
    }
}

// ---------------------------------------------------------------- CSR build
__global__ void deg_kernel(const int* __restrict__ dst, int* __restrict__ deg, int E) {
    int e = blockIdx.x * blockDim.x + threadIdx.x;
    if (e < E) atomicAdd(&deg[dst[e]], 1);
}

// ---- 3-phase multi-block exclusive scan (512 elements per block) ----
__global__ __launch_bounds__(256) void scan_phaseA(const int* __restrict__ deg,
        int* __restrict__ blocksum, int N) {
    __shared__ int red[256];
    int i0 = blockIdx.x * 512 + threadIdx.x * 2;
    int s = 0;
    if (i0 < N)     s += deg[i0];
    if (i0 + 1 < N) s += deg[i0 + 1];
    red[threadIdx.x] = s;
    __syncthreads();
    for (int off = 128; off; off >>= 1) {
        if (threadIdx.x < off) red[threadIdx.x] += red[threadIdx.x + off];
        __syncthreads();
    }
    if (threadIdx.x == 0) blocksum[blockIdx.x] = red[0];
}

__global__ __launch_bounds__(256) void scan_phaseB(int* __restrict__ blocksum, int NB,
        int* __restrict__ rowptr, int N) {
    __shared__ int part[256];
    int t = threadIdx.x;
    int v[4]; int sum = 0;
    #pragma unroll
    for (int j = 0; j < 4; ++j) {
        int i = 4 * t + j;
        v[j] = (i < NB) ? blocksum[i] : 0;
        sum += v[j];
    }
    part[t] = sum;
    __syncthreads();
    for (int off = 1; off < 256; off <<= 1) {
        int u = (t >= off) ? part[t - off] : 0;
        __syncthreads();
        part[t] += u;
        __syncthreads();
    }
    int run = part[t] - sum;   // exclusive prefix
    #pragma unroll
    for (int j = 0; j < 4; ++j) {
        int i = 4 * t + j;
        if (i < NB) blocksum[i] = run;
        run += v[j];
    }
    if (t == 255) rowptr[N] = part[255];
}

__global__ __launch_bounds__(256) void scan_phaseC(const int* __restrict__ deg,
        const int* __restrict__ blockoff, int* __restrict__ rowptr,
        int* __restrict__ cursor, int N) {
    __shared__ int part[256];
    int t = threadIdx.x;
    int i0 = blockIdx.x * 512 + 2 * t;
    int d0 = (i0 < N)     ? deg[i0]     : 0;
    int d1 = (i0 + 1 < N) ? deg[i0 + 1] : 0;
    int sum = d0 + d1;
    part[t] = sum;
    __syncthreads();
    for (int off = 1; off < 256; off <<= 1) {
        int u = (t >= off) ? part[t - off] : 0;
        __syncthreads();
        part[t] += u;
        __syncthreads();
    }
    int run = blockoff[blockIdx.x] + part[t] - sum;
    if (i0 < N)     { rowptr[i0] = run; cursor[i0] = run; }
    run += d0;
    if (i0 + 1 < N) { rowptr[i0 + 1] = run; cursor[i0 + 1] = run; }
}

__global__ void bucket_kernel(const int* __restrict__ src, const int* __restrict__ dst,
        int* __restrict__ cursor, int* __restrict__ ebuf, int E) {
    int e = blockIdx.x * blockDim.x + threadIdx.x;
    if (e < E) {
        int p = atomicAdd(&cursor[dst[e]], 1);
        ebuf[p] = src[e];
    }
}

// ------------------------------------------------------- weight pre-transpose
// Wt[fo*ldt + fi] = W[fi*cols + fo], output canonical bf16
__global__ void transpose_kernel(const void* __restrict__ W,
        __hip_bfloat16* __restrict__ Wt, int rows, int cols, int ldt,
        const int* __restrict__ flags) {
    int idx = blockIdx.x * blockDim.x + threadIdx.x;
    if (idx < rows * cols) {
        int fi = idx / cols, fo = idx % cols;
        Wt[fo * ldt + fi] = __float2bfloat16(loadf(W, idx, flags[1] != 0));
    }
}

// --------------------------------------------------------------- MFMA GEMM
// Compile-time KSTEPS (K = KSTEPS*32) so xf[] is statically indexed ->
// stays in VGPRs (R5's runtime-K version spilled xf to scratch: VGPR=32,
// MfmaUtil 3.4%, ~15k cyc/wave on scratch round-trips).
// out[node][fo] = sum_k X[node][k] * Wt[fo][k]  (+bias[fo]); out bf16 or f32.
// X split at K0 between X0/X1. One wave = 16-node stripe x all Ncols.
template<int KSTEPS>
__global__ __launch_bounds__(256) void gemm_mfma_t(
        const void* __restrict__ X0, const void* __restrict__ X1, int K0, int xflag,
        const __hip_bfloat16* __restrict__ Wt, const void* __restrict__ bias,
        void* __restrict__ outp, int ldo, int out_f32, int M, int Ncols,
        const int* __restrict__ flags) {
    constexpr int K = KSTEPS * 32;
    bool pf = flags[1] != 0;       // raw float inputs are f32
    bool xf32 = (xflag != 0) && pf;
    int wave = (blockIdx.x * blockDim.x + threadIdx.x) >> 6;
    int node_base = wave << 4;
    if (node_base >= M) return;
    int lane = threadIdx.x & 63;
    int quad = lane >> 4;          // 0..3
    int r = lane & 15;             // 0..15
    int node = node_base + r;
    int nodeL = min(node, M - 1);  // clamp for loads

    bf16x8 xf[KSTEPS];
    if (xf32) {
        #pragma unroll
        for (int ks = 0; ks < KSTEPS; ++ks) {
            int k = ks * 32 + quad * 8;
            const float* p = (k < K0)
                ? ((const float*)X0 + (size_t)nodeL * K0 + k)
                : ((const float*)X1 + (size_t)nodeL * (K - K0) + (k - K0));
            float4 a = *(const float4*)p;
            float4 b = *(const float4*)(p + 4);
            bf16x8 t;
            t[0] = f2bs(a.x); t[1] = f2bs(a.y); t[2] = f2bs(a.z); t[3] = f2bs(a.w);
            t[4] = f2bs(b.x); t[5] = f2bs(b.y); t[6] = f2bs(b.z); t[7] = f2bs(b.w);
            xf[ks] = t;
        }
    } else {
        #pragma unroll
        for (int ks = 0; ks < KSTEPS; ++ks) {
            int k = ks * 32 + quad * 8;
            const __hip_bfloat16* p = (k < K0)
                ? ((const __hip_bfloat16*)X0 + (size_t)nodeL * K0 + k)
                : ((const __hip_bfloat16*)X1 + (size_t)nodeL * (K - K0) + (k - K0));
            xf[ks] = *(const bf16x8*)p;
        }
    }

    int ntiles = Ncols >> 4;
    for (int ft = 0; ft < ntiles; ++ft) {
        f32x4 acc = {0.f, 0.f, 0.f, 0.f};
        const __hip_bfloat16* wrow = Wt + (size_t)(ft * 16 + r) * K + quad * 8;
        #pragma unroll
        for (int ks = 0; ks < KSTEPS; ++ks) {
            bf16x8 wf = *(const bf16x8*)(wrow + ks * 32);
            acc = __builtin_amdgcn_mfma_f32_16x16x32_bf16(wf, xf[ks], acc, 0, 0, 0);
        }
        // D layout: col = lane&15 -> node r, row = quad*4 + reg -> fo
        int fo = ft * 16 + quad * 4;
        float b0 = 0.f, b1 = 0.f, b2 = 0.f, b3 = 0.f;
        if (bias) {
            b0 = loadf(bias, fo + 0, pf); b1 = loadf(bias, fo + 1, pf);
            b2 = loadf(bias, fo + 2, pf); b3 = loadf(bias, fo + 3, pf);
        }
        if (node < M) {
            if (out_f32) {
                float4 res;
                res.x = acc[0] + b0; res.y = acc[1] + b1;
                res.z = acc[2] + b2; res.w = acc[3] + b3;
                *(float4*)((float*)outp + (size_t)node * ldo + fo) = res;
            } else {
                short4 res;
                res.x = f2bs(acc[0] + b0); res.y = f2bs(acc[1] + b1);
                res.z = f2bs(acc[2] + b2); res.w = f2bs(acc[3] + b3);
                *(short4*)((short*)outp + (size_t)node * ldo + fo) = res;
            }
        }
    }
}

// --------------------------------------- fused mean-agg + bias + lin_r + LN + ReLU
// yz bf16 [N][256]: cols 0..127 = y (projected neighbor feats), 128..255 = z (lin_r)
// One wave per node; lane handles features 2*lane, 2*lane+1. f32 accumulation.
// Neighbor loop is 8-way batched: 8 independent gathers in flight per wave.
__global__ __launch_bounds__(256) void agg_ln_relu(
        const __hip_bfloat16* __restrict__ yz, const int* __restrict__ rowptr,
        const int* __restrict__ ebuf,
        const void* __restrict__ bn, const void* __restrict__ g,
        const void* __restrict__ be, __hip_bfloat16* __restrict__ hout, int N,
        const int* __restrict__ flags) {
    int node = (blockIdx.x * blockDim.x + threadIdx.x) >> 6;
    if (node >= N) return;
    node = __builtin_amdgcn_readfirstlane(node);   // provably wave-uniform -> s_loads
    bool pf = flags[1] != 0;
    int lane = threadIdx.x & 63;
    int f = lane * 2;
    const short* yzs = (const short*)yz;
    int start = rowptr[node], end = rowptr[node + 1];
    float a0 = 0.f, a1 = 0.f;
    int i = start;
    for (; i + 8 <= end; i += 8) {
        int n0 = ebuf[i + 0], n1 = ebuf[i + 1], n2 = ebuf[i + 2], n3 = ebuf[i + 3];
        int n4 = ebuf[i + 4], n5 = ebuf[i + 5], n6 = ebuf[i + 6], n7 = ebuf[i + 7];
        short2 t0 = *(const short2*)(yzs + (size_t)n0 * 256 + f);
        short2 t1 = *(const short2*)(yzs + (size_t)n1 * 256 + f);
        short2 t2 = *(const short2*)(yzs + (size_t)n2 * 256 + f);
        short2 t3 = *(const short2*)(yzs + (size_t)n3 * 256 + f);
        short2 t4 = *(const short2*)(yzs + (size_t)n4 * 256 + f);
        short2 t5 = *(const short2*)(yzs + (size_t)n5 * 256 + f);
        short2 t6 = *(const short2*)(yzs + (size_t)n6 * 256 + f);
        short2 t7 = *(const short2*)(yzs + (size_t)n7 * 256 + f);
        a0 += bs2f(t0.x) + bs2f(t1.x) + bs2f(t2.x) + bs2f(t3.x)
            + bs2f(t4.x) + bs2f(t5.x) + bs2f(t6.x) + bs2f(t7.x);
        a1 += bs2f(t0.y) + bs2f(t1.y) + bs2f(t2.y) + bs2f(t3.y)
            + bs2f(t4.y) + bs2f(t5.y) + bs2f(t6.y) + bs2f(t7.y);
    }
    for (; i + 2 <= end; i += 2) {
        int n0 = ebuf[i + 0], n1 = ebuf[i + 1];
        short2 t0 = *(const short2*)(yzs + (size_t)n0 * 256 + f);
        short2 t1 = *(const short2*)(yzs + (size_t)n1 * 256 + f);
        a0 += bs2f(t0.x) + bs2f(t1.x);
        a1 += bs2f(t0.y) + bs2f(t1.y);
    }
    if (i < end) {
        int n0 = ebuf[i];
        short2 t0 = *(const short2*)(yzs + (size_t)n0 * 256 + f);
        a0 += bs2f(t0.x);
        a1 += bs2f(t0.y);
    }
    float inv = 1.f / fmaxf((float)(end - start), 1.f);
    short2 zt = *(const short2*)(yzs + (size_t)node * 256 + 128 + f);
    float v0 = a0 * inv + loadf(bn, f, pf)     + bs2f(zt.x);
    float v1 = a1 * inv + loadf(bn, f + 1, pf) + bs2f(zt.y);
    float s = v0 + v1;
    #pragma unroll
    for (int off = 32; off > 0; off >>= 1) s += __shfl_xor(s, off, 64);
    float mu = s * (1.f / 128.f);
    float d0 = v0 - mu, d1 = v1 - mu;
    float q = d0 * d0 + d1 * d1;
    #pragma unroll
    for (int off = 32; off > 0; off >>= 1) q += __shfl_xor(q, off, 64);
    float rstd = rsqrtf(q * (1.f / 128.f) + 1e-5f);
    float o0 = fmaxf(d0 * rstd * loadf(g, f, pf)     + loadf(be, f, pf),     0.f);
    float o1 = fmaxf(d1 * rstd * loadf(g, f + 1, pf) + loadf(be, f + 1, pf), 0.f);
    short* hp = (short*)hout + (size_t)node * 128 + f;
    hp[0] = f2bs(o0);
    hp[1] = f2bs(o1);
}

// ------------------------------------------------------------- MLP head
// out = relu(feats @ Wh1 + bh1) @ Wh2 + bh2, feats f32 [N][128]
// output dtype follows flags[1]: f32 if inputs f32, else bf16
__global__ __launch_bounds__(256) void head_kernel(
        const float* __restrict__ feats, const void* __restrict__ Wh1,
        const void* __restrict__ bh1, const void* __restrict__ Wh2,
        const void* __restrict__ bh2, void* __restrict__ outp, int N,
        const int* __restrict__ flags) {
    __shared__ float sfe[8 * 128];
    __shared__ float shid[8 * 32];
    bool pf = flags[1] != 0;
    int nb = blockIdx.x * 8;
    int tid = threadIdx.x;
    {
        int i = tid * 4;
        int gnode = nb + (i >> 7);
        float4 v = make_float4(0.f, 0.f, 0.f, 0.f);
        if (gnode < N) v = *(const float4*)(feats + (size_t)gnode * 128 + (i & 127));
        *(float4*)(sfe + i) = v;
    }
    __syncthreads();
    {
        int nloc = tid >> 5, col = tid & 31;
        float acc = loadf(bh1, col, pf);
        const float* fr = sfe + nloc * 128;
        #pragma unroll 8
        for (int k = 0; k < 128; ++k) acc += fr[k] * loadf(Wh1, k * 32 + col, pf);
        shid[nloc * 32 + col] = fmaxf(acc, 0.f);
    }
    __syncthreads();
    if (tid < 128) {
        int nloc = tid >> 4, col = tid & 15;
        int gnode = nb + nloc;
        if (gnode < N) {
            float acc = loadf(bh2, col, pf);
            const float* hr = shid + nloc * 32;
            #pragma unroll
            for (int k = 0; k < 32; ++k) acc += hr[k] * loadf(Wh2, k * 16 + col, pf);
            if (pf) ((float*)outp)[(size_t)gnode * 16 + col] = acc;
            else    ((__hip_bfloat16*)outp)[(size_t)gnode * 16 + col] = __float2bfloat16(acc);
        }
    }
}

// ---------------------------------------------------------------- launcher
extern "C" void kernel_launch(void* const* d_in, const int* in_sizes, int n_in,
                              void* d_out, int out_size, void* d_ws, size_t ws_size,
                              hipStream_t stream) {
    const void* x    = d_in[0];
    const unsigned* ei = (const unsigned*)d_in[1];
    const void* Wnl0 = d_in[2];
    const void* bnl0 = d_in[3];
    const void* Wr0  = d_in[4];
    const void* Wnl1 = d_in[5];
    const void* bnl1 = d_in[6];
    const void* Wr1  = d_in[7];
    const void* g0   = d_in[8];
    const void* be0  = d_in[9];
    const void* g1   = d_in[10];
    const void* be1  = d_in[11];
    const void* Wjk  = d_in[12];
    const void* bjk  = d_in[13];
    const void* Wh1  = d_in[14];
    const void* bh1  = d_in[15];
    const void* Wh2  = d_in[16];
    const void* bh2  = d_in[17];

    const int N = in_sizes[0] / 256;
    const int E = in_sizes[1] / 2;

    char* ws = (char*)d_ws;
    size_t off = 0;
    auto alloc = [&](size_t bytes) -> void* {
        void* p = ws + off;
        off = (off + bytes + 255) & ~(size_t)255;
        return p;
    };
    int* flags  = (int*)alloc(256);
    int* src    = (int*)alloc((size_t)E * 4);
    int* dst    = (int*)alloc((size_t)E * 4);
    int* rowptr = (int*)alloc((size_t)(N + 1) * 4);
    int* deg    = (int*)alloc((size_t)N * 4);
    int* cursor = (int*)alloc((size_t)N * 4);
    int* ebuf   = (int*)alloc((size_t)E * 4);
    int* blocksum = (int*)alloc(1024 * 4);
    __hip_bfloat16* Wt0  = (__hip_bfloat16*)alloc(256 * 256 * 2);
    __hip_bfloat16* Wt1  = (__hip_bfloat16*)alloc(256 * 128 * 2);
    __hip_bfloat16* Wtjk = (__hip_bfloat16*)alloc(128 * 256 * 2);
    __hip_bfloat16* yz = (__hip_bfloat16*)alloc((size_t)N * 256 * 2);   // also feats f32 [N][128]
    __hip_bfloat16* h0 = (__hip_bfloat16*)alloc((size_t)N * 128 * 2);
    __hip_bfloat16* h1 = (__hip_bfloat16*)alloc((size_t)N * 128 * 2);
    float* feats = (float*)yz;   // yz dead after second agg; same byte size

    // dtype detection + canonical edge decode
    detect_kernel<<<1, 256, 0, stream>>>(ei, (const unsigned short*)x, flags);
    int eb = (E + 255) / 256;
    decode_edges<<<eb, 256, 0, stream>>>(ei, E, flags, src, dst);

    // CSR build (multi-block 3-phase scan; 512 elements per block)
    (void)hipMemsetAsync(deg, 0, (size_t)N * 4, stream);
    deg_kernel<<<eb, 256, 0, stream>>>(dst, deg, E);
    int NB = (N + 511) / 512;
    scan_phaseA<<<NB, 256, 0, stream>>>(deg, blocksum, N);
    scan_phaseB<<<1, 256, 0, stream>>>(blocksum, NB, rowptr, N);
    scan_phaseC<<<NB, 256, 0, stream>>>(deg, blocksum, rowptr, cursor, N);
    bucket_kernel<<<eb, 256, 0, stream>>>(src, dst, cursor, ebuf, E);

    // Weight transposes: Wt0 = [Wnl0^T ; Wr0^T] (256 rows x K=256),
    // Wt1 = [Wnl1^T ; Wr1^T] (256 rows x K=128), Wtjk = Wjk^T (128 rows x K=256)
    transpose_kernel<<<(256 * 128 + 255) / 256, 256, 0, stream>>>(Wnl0, Wt0, 256, 128, 256, flags);
    transpose_kernel<<<(256 * 128 + 255) / 256, 256, 0, stream>>>(Wr0,  Wt0 + 128 * 256, 256, 128, 256, flags);
    transpose_kernel<<<(128 * 128 + 255) / 256, 256, 0, stream>>>(Wnl1, Wt1, 128, 128, 128, flags);
    transpose_kernel<<<(128 * 128 + 255) / 256, 256, 0, stream>>>(Wr1,  Wt1 + 128 * 128, 128, 128, 128, flags);
    transpose_kernel<<<(256 * 128 + 255) / 256, 256, 0, stream>>>(Wjk,  Wtjk, 256, 128, 256, flags);

    int gwaves = (N + 15) / 16;
    int gblocks = (gwaves * 64 + 255) / 256;
    int ablocks = (int)(((size_t)N * 64 + 255) / 256);

    // layer 0: project (y0 = x@Wnl0, z0 = x@Wr0) -> agg+LN+ReLU -> h0
    gemm_mfma_t<8><<<gblocks, 256, 0, stream>>>(x, x, 256, 1, Wt0, nullptr, yz, 256, 0, N, 256, flags);
    agg_ln_relu<<<ablocks, 256, 0, stream>>>(yz, rowptr, ebuf, bnl0, g0, be0, h0, N, flags);

    // layer 1 (K=128)
    gemm_mfma_t<4><<<gblocks, 256, 0, stream>>>(h0, h0, 128, 0, Wt1, nullptr, yz, 256, 0, N, 256, flags);
    agg_ln_relu<<<ablocks, 256, 0, stream>>>(yz, rowptr, ebuf, bnl1, g1, be1, h1, N, flags);

    // JK: feats = [h0|h1] @ Wjk + bjk   (K split 128/128), f32 output
    gemm_mfma_t<8><<<gblocks, 256, 0, stream>>>(h0, h1, 128, 0, Wtjk, bjk, feats, 128, 1, N, 128, flags);

    // MLP head (output dtype follows detected float dtype)
    head_kernel<<<(N + 7) / 8, 256, 0, stream>>>(feats, Wh1, bh1, Wh2, bh2, d_out, N, flags);
}

// Round 7
// 714.139 us; speedup vs baseline: 1.7435x; 1.1750x over previous
//
#include <hip/hip_runtime.h>
#include <hip/hip_bf16.h>

typedef __attribute__((ext_vector_type(8))) short bf16x8;   // 8 bf16 = 4 VGPRs
typedef __attribute__((ext_vector_type(4))) float f32x4;    // 4 f32 acc

static __device__ __forceinline__ float bf2f(__hip_bfloat16 v) { return __bfloat162float(v); }

static __device__ __forceinline__ float bs2f(short s) {
    unsigned u = ((unsigned)(unsigned short)s) << 16;
    float f; __builtin_memcpy(&f, &u, 4); return f;
}
static __device__ __forceinline__ short f2bs(float v) {
    __hip_bfloat16 b = __float2bfloat16(v);
    short s; __builtin_memcpy(&s, &b, 2); return s;
}
// read element i of a float array that is either f32 or bf16
static __device__ __forceinline__ float loadf(const void* p, int i, bool f32) {
    if (f32) return ((const float*)p)[i];
    return bf2f(((const __hip_bfloat16*)p)[i]);
}

// ------------------------------------------------- runtime dtype detection
// flags[0] = 1 if edge_index is int64 (odd 32-bit words of first 2048 pairs all 0)
// flags[1] = 1 if float inputs are f32 (bf16 view of x has huge-exponent lanes)
__global__ __launch_bounds__(256) void detect_kernel(const unsigned* __restrict__ ew,
        const unsigned short* __restrict__ xw, int* __restrict__ flags) {
    __shared__ int s_odd, s_f32;
    int t = threadIdx.x;
    if (t == 0) { s_odd = 0; s_f32 = 0; }
    __syncthreads();
    unsigned acc = 0;
    for (int i = t; i < 2048; i += 256) acc |= ew[2 * i + 1];
    if (acc) atomicOr(&s_odd, 1);
    int f32ev = 0;
    for (int i = t; i < 4096; i += 256) {
        unsigned e = (xw[i] >> 7) & 0xFF;          // bf16 exponent field
        if (e >= 0xC0) f32ev = 1;                  // impossible for real bf16 data
    }
    if (f32ev) atomicOr(&s_f32, 1);
    __syncthreads();
    if (t == 0) { flags[0] = s_odd ? 0 : 1; flags[1] = s_f32; }
}

// decode edge_index (int32 or int64 layout) into canonical int32 src/dst
__global__ void decode_edges(const unsigned* __restrict__ ew, int E,
        const int* __restrict__ flags, int* __restrict__ src, int* __restrict__ dst) {
    int e = blockIdx.x * blockDim.x + threadIdx.x;
    if (e >= E) return;
    if (flags[0]) {      // int64: words [2e] lo; dst row starts at word 2E
        src[e] = (int)ew[2 * (size_t)e];
        dst[e] = (int)ew[2 * (size_t)E + 2 * (size_t)e];
    } else {
        src[e] = (int)ew[e];
        dst[e] = (int)ew[(size_t)E + e];
    }
}

// ---------------------------------------------------------------- CSR build
__global__ void deg_kernel(const int* __restrict__ dst, int* __restrict__ deg, int E) {
    int e = blockIdx.x * blockDim.x + threadIdx.x;
    if (e < E) atomicAdd(&deg[dst[e]], 1);
}

// ---- 3-phase multi-block exclusive scan (512 elements per block) ----
__global__ __launch_bounds__(256) void scan_phaseA(const int* __restrict__ deg,
        int* __restrict__ blocksum, int N) {
    __shared__ int red[256];
    int i0 = blockIdx.x * 512 + threadIdx.x * 2;
    int s = 0;
    if (i0 < N)     s += deg[i0];
    if (i0 + 1 < N) s += deg[i0 + 1];
    red[threadIdx.x] = s;
    __syncthreads();
    for (int off = 128; off; off >>= 1) {
        if (threadIdx.x < off) red[threadIdx.x] += red[threadIdx.x + off];
        __syncthreads();
    }
    if (threadIdx.x == 0) blocksum[blockIdx.x] = red[0];
}

__global__ __launch_bounds__(256) void scan_phaseB(int* __restrict__ blocksum, int NB,
        int* __restrict__ rowptr, int N) {
    __shared__ int part[256];
    int t = threadIdx.x;
    int v[4]; int sum = 0;
    #pragma unroll
    for (int j = 0; j < 4; ++j) {
        int i = 4 * t + j;
        v[j] = (i < NB) ? blocksum[i] : 0;
        sum += v[j];
    }
    part[t] = sum;
    __syncthreads();
    for (int off = 1; off < 256; off <<= 1) {
        int u = (t >= off) ? part[t - off] : 0;
        __syncthreads();
        part[t] += u;
        __syncthreads();
    }
    int run = part[t] - sum;   // exclusive prefix
    #pragma unroll
    for (int j = 0; j < 4; ++j) {
        int i = 4 * t + j;
        if (i < NB) blocksum[i] = run;
        run += v[j];
    }
    if (t == 255) rowptr[N] = part[255];
}

__global__ __launch_bounds__(256) void scan_phaseC(const int* __restrict__ deg,
        const int* __restrict__ blockoff, int* __restrict__ rowptr,
        int* __restrict__ cursor, int N) {
    __shared__ int part[256];
    int t = threadIdx.x;
    int i0 = blockIdx.x * 512 + 2 * t;
    int d0 = (i0 < N)     ? deg[i0]     : 0;
    int d1 = (i0 + 1 < N) ? deg[i0 + 1] : 0;
    int sum = d0 + d1;
    part[t] = sum;
    __syncthreads();
    for (int off = 1; off < 256; off <<= 1) {
        int u = (t >= off) ? part[t - off] : 0;
        __syncthreads();
        part[t] += u;
        __syncthreads();
    }
    int run = blockoff[blockIdx.x] + part[t] - sum;
    if (i0 < N)     { rowptr[i0] = run; cursor[i0] = run; }
    run += d0;
    if (i0 + 1 < N) { rowptr[i0 + 1] = run; cursor[i0 + 1] = run; }
}

__global__ void bucket_kernel(const int* __restrict__ src, const int* __restrict__ dst,
        int* __restrict__ cursor, int* __restrict__ ebuf, int E) {
    int e = blockIdx.x * blockDim.x + threadIdx.x;
    if (e < E) {
        int p = atomicAdd(&cursor[dst[e]], 1);
        ebuf[p] = src[e];
    }
}

// ------------------------------------------------------- weight pre-transpose
// Wt[fo*ldt + fi] = W[fi*cols + fo], output canonical bf16
__global__ void transpose_kernel(const void* __restrict__ W,
        __hip_bfloat16* __restrict__ Wt, int rows, int cols, int ldt,
        const int* __restrict__ flags) {
    int idx = blockIdx.x * blockDim.x + threadIdx.x;
    if (idx < rows * cols) {
        int fi = idx / cols, fo = idx % cols;
        Wt[fo * ldt + fi] = __float2bfloat16(loadf(W, idx, flags[1] != 0));
    }
}

// --------------------------------------------------------------- MFMA GEMM v4
// Block = 64 nodes (4 waves x 16-node stripes). Output cols processed in
// phases of 64 (4 ftiles). Per phase the block stages the 64-col W-slab into
// LDS in fragment-contiguous layout (Wf[ft][ks][lane][8] -> ds_read_b128 is a
// conflict-free contiguous 1KB/instr), then each wave runs 4 independent
// 8-MFMA chains. Fixes R5/R6's per-wave 128KB L2 W re-read + serialized
// dependent loads (MfmaUtil 3.4%, all pipes idle).
// out[node][fo] = sum_k X[node][k] * Wt[fo][k]  (+bias[fo]); out bf16 or f32.
// X split at K0 between X0/X1; xf loaded once per wave (proven R3 path).
template<int KSTEPS>
__global__ __launch_bounds__(256) void gemm_v4(
        const void* __restrict__ X0, const void* __restrict__ X1, int K0, int xflag,
        const __hip_bfloat16* __restrict__ Wt, const void* __restrict__ bias,
        void* __restrict__ outp, int ldo, int out_f32, int M, int Ncols,
        const int* __restrict__ flags) {
    constexpr int K = KSTEPS * 32;
    constexpr int CH = K / 8;              // 16B chunks per W row
    __shared__ short Wf[4 * KSTEPS * 64 * 8];   // 4 ftiles per phase (32KB @ K=256)
    bool pf = flags[1] != 0;
    bool xf32 = (xflag != 0) && pf;
    int tid = threadIdx.x;
    int wave = tid >> 6, lane = tid & 63;
    int quad = lane >> 4, r = lane & 15;
    int node = blockIdx.x * 64 + wave * 16 + r;
    int nodeL = min(node, M - 1);          // clamp loads; store guarded

    // X fragments: held in regs for the whole kernel (read once)
    bf16x8 xf[KSTEPS];
    if (xf32) {
        #pragma unroll
        for (int ks = 0; ks < KSTEPS; ++ks) {
            int k = ks * 32 + quad * 8;
            const float* p = (k < K0)
                ? ((const float*)X0 + (size_t)nodeL * K0 + k)
                : ((const float*)X1 + (size_t)nodeL * (K - K0) + (k - K0));
            float4 a = *(const float4*)p;
            float4 b = *(const float4*)(p + 4);
            bf16x8 t;
            t[0] = f2bs(a.x); t[1] = f2bs(a.y); t[2] = f2bs(a.z); t[3] = f2bs(a.w);
            t[4] = f2bs(b.x); t[5] = f2bs(b.y); t[6] = f2bs(b.z); t[7] = f2bs(b.w);
            xf[ks] = t;
        }
    } else {
        #pragma unroll
        for (int ks = 0; ks < KSTEPS; ++ks) {
            int k = ks * 32 + quad * 8;
            const __hip_bfloat16* p = (k < K0)
                ? ((const __hip_bfloat16*)X0 + (size_t)nodeL * K0 + k)
                : ((const __hip_bfloat16*)X1 + (size_t)nodeL * (K - K0) + (k - K0));
            xf[ks] = *(const bf16x8*)p;
        }
    }

    int nphases = Ncols >> 6;              // 64 cols per phase
    for (int p = 0; p < nphases; ++p) {
        if (p) __syncthreads();            // protect Wf from previous phase's readers
        // ---- stage 64 W rows (cols p*64..p*64+63) into fragment layout ----
        #pragma unroll
        for (int i = 0; i < KSTEPS; ++i) {         // 64*CH/256 == KSTEPS iters
            int idx = i * 256 + tid;
            int row_l = idx / CH, c = idx % CH;    // consecutive tid -> consecutive c (coalesced)
            uint4 v = *(const uint4*)((const short*)Wt + (size_t)(p * 64 + row_l) * K + c * 8);
            int ftl = row_l >> 4, rr = row_l & 15;
            int ks = c >> 2, q = c & 3;
            *(uint4*)(Wf + (size_t)(((ftl * KSTEPS + ks) * 64) + q * 16 + rr) * 8) = v;
        }
        __syncthreads();
        // ---- compute: 4 independent ftile chains ----
        #pragma unroll
        for (int ftl = 0; ftl < 4; ++ftl) {
            f32x4 acc = {0.f, 0.f, 0.f, 0.f};
            #pragma unroll
            for (int ks = 0; ks < KSTEPS; ++ks) {
                bf16x8 wf = *(const bf16x8*)(Wf + (size_t)((ftl * KSTEPS + ks) * 64 + lane) * 8);
                acc = __builtin_amdgcn_mfma_f32_16x16x32_bf16(wf, xf[ks], acc, 0, 0, 0);
            }
            // D layout: col = lane&15 -> node r, row = quad*4 + reg -> fo
            int fo = p * 64 + ftl * 16 + quad * 4;
            float b0 = 0.f, b1 = 0.f, b2 = 0.f, b3 = 0.f;
            if (bias) {
                b0 = loadf(bias, fo + 0, pf); b1 = loadf(bias, fo + 1, pf);
                b2 = loadf(bias, fo + 2, pf); b3 = loadf(bias, fo + 3, pf);
            }
            if (node < M) {
                if (out_f32) {
                    float4 res;
                    res.x = acc[0] + b0; res.y = acc[1] + b1;
                    res.z = acc[2] + b2; res.w = acc[3] + b3;
                    *(float4*)((float*)outp + (size_t)node * ldo + fo) = res;
                } else {
                    short4 res;
                    res.x = f2bs(acc[0] + b0); res.y = f2bs(acc[1] + b1);
                    res.z = f2bs(acc[2] + b2); res.w = f2bs(acc[3] + b3);
                    *(short4*)((short*)outp + (size_t)node * ldo + fo) = res;
                }
            }
        }
    }
}

// --------------------------------------- fused mean-agg + bias + lin_r + LN + ReLU
// yz bf16 [N][256]: cols 0..127 = y (projected neighbor feats), 128..255 = z (lin_r)
// One wave per node; lane handles features 2*lane, 2*lane+1. f32 accumulation.
// Neighbor loop is 8-way batched: 8 independent gathers in flight per wave.
__global__ __launch_bounds__(256) void agg_ln_relu(
        const __hip_bfloat16* __restrict__ yz, const int* __restrict__ rowptr,
        const int* __restrict__ ebuf,
        const void* __restrict__ bn, const void* __restrict__ g,
        const void* __restrict__ be, __hip_bfloat16* __restrict__ hout, int N,
        const int* __restrict__ flags) {
    int node = (blockIdx.x * blockDim.x + threadIdx.x) >> 6;
    if (node >= N) return;
    node = __builtin_amdgcn_readfirstlane(node);   // provably wave-uniform -> s_loads
    bool pf = flags[1] != 0;
    int lane = threadIdx.x & 63;
    int f = lane * 2;
    const short* yzs = (const short*)yz;
    int start = rowptr[node], end = rowptr[node + 1];
    float a0 = 0.f, a1 = 0.f;
    int i = start;
    for (; i + 8 <= end; i += 8) {
        int n0 = ebuf[i + 0], n1 = ebuf[i + 1], n2 = ebuf[i + 2], n3 = ebuf[i + 3];
        int n4 = ebuf[i + 4], n5 = ebuf[i + 5], n6 = ebuf[i + 6], n7 = ebuf[i + 7];
        short2 t0 = *(const short2*)(yzs + (size_t)n0 * 256 + f);
        short2 t1 = *(const short2*)(yzs + (size_t)n1 * 256 + f);
        short2 t2 = *(const short2*)(yzs + (size_t)n2 * 256 + f);
        short2 t3 = *(const short2*)(yzs + (size_t)n3 * 256 + f);
        short2 t4 = *(const short2*)(yzs + (size_t)n4 * 256 + f);
        short2 t5 = *(const short2*)(yzs + (size_t)n5 * 256 + f);
        short2 t6 = *(const short2*)(yzs + (size_t)n6 * 256 + f);
        short2 t7 = *(const short2*)(yzs + (size_t)n7 * 256 + f);
        a0 += bs2f(t0.x) + bs2f(t1.x) + bs2f(t2.x) + bs2f(t3.x)
            + bs2f(t4.x) + bs2f(t5.x) + bs2f(t6.x) + bs2f(t7.x);
        a1 += bs2f(t0.y) + bs2f(t1.y) + bs2f(t2.y) + bs2f(t3.y)
            + bs2f(t4.y) + bs2f(t5.y) + bs2f(t6.y) + bs2f(t7.y);
    }
    for (; i + 2 <= end; i += 2) {
        int n0 = ebuf[i + 0], n1 = ebuf[i + 1];
        short2 t0 = *(const short2*)(yzs + (size_t)n0 * 256 + f);
        short2 t1 = *(const short2*)(yzs + (size_t)n1 * 256 + f);
        a0 += bs2f(t0.x) + bs2f(t1.x);
        a1 += bs2f(t0.y) + bs2f(t1.y);
    }
    if (i < end) {
        int n0 = ebuf[i];
        short2 t0 = *(const short2*)(yzs + (size_t)n0 * 256 + f);
        a0 += bs2f(t0.x);
        a1 += bs2f(t0.y);
    }
    float inv = 1.f / fmaxf((float)(end - start), 1.f);
    short2 zt = *(const short2*)(yzs + (size_t)node * 256 + 128 + f);
    float v0 = a0 * inv + loadf(bn, f, pf)     + bs2f(zt.x);
    float v1 = a1 * inv + loadf(bn, f + 1, pf) + bs2f(zt.y);
    float s = v0 + v1;
    #pragma unroll
    for (int off = 32; off > 0; off >>= 1) s += __shfl_xor(s, off, 64);
    float mu = s * (1.f / 128.f);
    float d0 = v0 - mu, d1 = v1 - mu;
    float q = d0 * d0 + d1 * d1;
    #pragma unroll
    for (int off = 32; off > 0; off >>= 1) q += __shfl_xor(q, off, 64);
    float rstd = rsqrtf(q * (1.f / 128.f) + 1e-5f);
    float o0 = fmaxf(d0 * rstd * loadf(g, f, pf)     + loadf(be, f, pf),     0.f);
    float o1 = fmaxf(d1 * rstd * loadf(g, f + 1, pf) + loadf(be, f + 1, pf), 0.f);
    short* hp = (short*)hout + (size_t)node * 128 + f;
    hp[0] = f2bs(o0);
    hp[1] = f2bs(o1);
}

// ------------------------------------------------------------- MLP head
// out = relu(feats @ Wh1 + bh1) @ Wh2 + bh2, feats f32 [N][128]
// output dtype follows flags[1]: f32 if inputs f32, else bf16
__global__ __launch_bounds__(256) void head_kernel(
        const float* __restrict__ feats, const void* __restrict__ Wh1,
        const void* __restrict__ bh1, const void* __restrict__ Wh2,
        const void* __restrict__ bh2, void* __restrict__ outp, int N,
        const int* __restrict__ flags) {
    __shared__ float sfe[8 * 128];
    __shared__ float shid[8 * 32];
    bool pf = flags[1] != 0;
    int nb = blockIdx.x * 8;
    int tid = threadIdx.x;
    {
        int i = tid * 4;
        int gnode = nb + (i >> 7);
        float4 v = make_float4(0.f, 0.f, 0.f, 0.f);
        if (gnode < N) v = *(const float4*)(feats + (size_t)gnode * 128 + (i & 127));
        *(float4*)(sfe + i) = v;
    }
    __syncthreads();
    {
        int nloc = tid >> 5, col = tid & 31;
        float acc = loadf(bh1, col, pf);
        const float* fr = sfe + nloc * 128;
        #pragma unroll 8
        for (int k = 0; k < 128; ++k) acc += fr[k] * loadf(Wh1, k * 32 + col, pf);
        shid[nloc * 32 + col] = fmaxf(acc, 0.f);
    }
    __syncthreads();
    if (tid < 128) {
        int nloc = tid >> 4, col = tid & 15;
        int gnode = nb + nloc;
        if (gnode < N) {
            float acc = loadf(bh2, col, pf);
            const float* hr = shid + nloc * 32;
            #pragma unroll
            for (int k = 0; k < 32; ++k) acc += hr[k] * loadf(Wh2, k * 16 + col, pf);
            if (pf) ((float*)outp)[(size_t)gnode * 16 + col] = acc;
            else    ((__hip_bfloat16*)outp)[(size_t)gnode * 16 + col] = __float2bfloat16(acc);
        }
    }
}

// ---------------------------------------------------------------- launcher
extern "C" void kernel_launch(void* const* d_in, const int* in_sizes, int n_in,
                              void* d_out, int out_size, void* d_ws, size_t ws_size,
                              hipStream_t stream) {
    const void* x    = d_in[0];
    const unsigned* ei = (const unsigned*)d_in[1];
    const void* Wnl0 = d_in[2];
    const void* bnl0 = d_in[3];
    const void* Wr0  = d_in[4];
    const void* Wnl1 = d_in[5];
    const void* bnl1 = d_in[6];
    const void* Wr1  = d_in[7];
    const void* g0   = d_in[8];
    const void* be0  = d_in[9];
    const void* g1   = d_in[10];
    const void* be1  = d_in[11];
    const void* Wjk  = d_in[12];
    const void* bjk  = d_in[13];
    const void* Wh1  = d_in[14];
    const void* bh1  = d_in[15];
    const void* Wh2  = d_in[16];
    const void* bh2  = d_in[17];

    const int N = in_sizes[0] / 256;
    const int E = in_sizes[1] / 2;

    char* ws = (char*)d_ws;
    size_t off = 0;
    auto alloc = [&](size_t bytes) -> void* {
        void* p = ws + off;
        off = (off + bytes + 255) & ~(size_t)255;
        return p;
    };
    int* flags  = (int*)alloc(256);
    int* src    = (int*)alloc((size_t)E * 4);
    int* dst    = (int*)alloc((size_t)E * 4);
    int* rowptr = (int*)alloc((size_t)(N + 1) * 4);
    int* deg    = (int*)alloc((size_t)N * 4);
    int* cursor = (int*)alloc((size_t)N * 4);
    int* ebuf   = (int*)alloc((size_t)E * 4);
    int* blocksum = (int*)alloc(1024 * 4);
    __hip_bfloat16* Wt0  = (__hip_bfloat16*)alloc(256 * 256 * 2);
    __hip_bfloat16* Wt1  = (__hip_bfloat16*)alloc(256 * 128 * 2);
    __hip_bfloat16* Wtjk = (__hip_bfloat16*)alloc(128 * 256 * 2);
    __hip_bfloat16* yz = (__hip_bfloat16*)alloc((size_t)N * 256 * 2);   // also feats f32 [N][128]
    __hip_bfloat16* h0 = (__hip_bfloat16*)alloc((size_t)N * 128 * 2);
    __hip_bfloat16* h1 = (__hip_bfloat16*)alloc((size_t)N * 128 * 2);
    float* feats = (float*)yz;   // yz dead after second agg; same byte size

    // dtype detection + canonical edge decode
    detect_kernel<<<1, 256, 0, stream>>>(ei, (const unsigned short*)x, flags);
    int eb = (E + 255) / 256;
    decode_edges<<<eb, 256, 0, stream>>>(ei, E, flags, src, dst);

    // CSR build (multi-block 3-phase scan; 512 elements per block)
    (void)hipMemsetAsync(deg, 0, (size_t)N * 4, stream);
    deg_kernel<<<eb, 256, 0, stream>>>(dst, deg, E);
    int NB = (N + 511) / 512;
    scan_phaseA<<<NB, 256, 0, stream>>>(deg, blocksum, N);
    scan_phaseB<<<1, 256, 0, stream>>>(blocksum, NB, rowptr, N);
    scan_phaseC<<<NB, 256, 0, stream>>>(deg, blocksum, rowptr, cursor, N);
    bucket_kernel<<<eb, 256, 0, stream>>>(src, dst, cursor, ebuf, E);

    // Weight transposes: Wt0 = [Wnl0^T ; Wr0^T] (256 rows x K=256),
    // Wt1 = [Wnl1^T ; Wr1^T] (256 rows x K=128), Wtjk = Wjk^T (128 rows x K=256)
    transpose_kernel<<<(256 * 128 + 255) / 256, 256, 0, stream>>>(Wnl0, Wt0, 256, 128, 256, flags);
    transpose_kernel<<<(256 * 128 + 255) / 256, 256, 0, stream>>>(Wr0,  Wt0 + 128 * 256, 256, 128, 256, flags);
    transpose_kernel<<<(128 * 128 + 255) / 256, 256, 0, stream>>>(Wnl1, Wt1, 128, 128, 128, flags);
    transpose_kernel<<<(128 * 128 + 255) / 256, 256, 0, stream>>>(Wr1,  Wt1 + 128 * 128, 128, 128, 128, flags);
    transpose_kernel<<<(256 * 128 + 255) / 256, 256, 0, stream>>>(Wjk,  Wtjk, 256, 128, 256, flags);

    int gblocks = (N + 63) / 64;    // 64 nodes per block
    int ablocks = (int)(((size_t)N * 64 + 255) / 256);

    // layer 0: project (y0 = x@Wnl0, z0 = x@Wr0) -> agg+LN+ReLU -> h0
    gemm_v4<8><<<gblocks, 256, 0, stream>>>(x, x, 256, 1, Wt0, nullptr, yz, 256, 0, N, 256, flags);
    agg_ln_relu<<<ablocks, 256, 0, stream>>>(yz, rowptr, ebuf, bnl0, g0, be0, h0, N, flags);

    // layer 1 (K=128)
    gemm_v4<4><<<gblocks, 256, 0, stream>>>(h0, h0, 128, 0, Wt1, nullptr, yz, 256, 0, N, 256, flags);
    agg_ln_relu<<<ablocks, 256, 0, stream>>>(yz, rowptr, ebuf, bnl1, g1, be1, h1, N, flags);

    // JK: feats = [h0|h1] @ Wjk + bjk   (K split 128/128), f32 output
    gemm_v4<8><<<gblocks, 256, 0, stream>>>(h0, h1, 128, 0, Wtjk, bjk, feats, 128, 1, N, 128, flags);

    // MLP head (output dtype follows detected float dtype)
    head_kernel<<<(N + 7) / 8, 256, 0, stream>>>(feats, Wh1, bh1, Wh2, bh2, d_out, N, flags);
}

// Round 8
// 588.531 us; speedup vs baseline: 2.1156x; 1.2134x over previous
//
#include <hip/hip_runtime.h>
#include <hip/hip_bf16.h>

typedef __attribute__((ext_vector_type(8))) short bf16x8;   // 8 bf16 = 4 VGPRs
typedef __attribute__((ext_vector_type(4))) float f32x4;    // 4 f32 acc

static __device__ __forceinline__ float bf2f(__hip_bfloat16 v) { return __bfloat162float(v); }

static __device__ __forceinline__ float bs2f(short s) {
    unsigned u = ((unsigned)(unsigned short)s) << 16;
    float f; __builtin_memcpy(&f, &u, 4); return f;
}
static __device__ __forceinline__ short f2bs(float v) {
    __hip_bfloat16 b = __float2bfloat16(v);
    short s; __builtin_memcpy(&s, &b, 2); return s;
}
// read element i of a float array that is either f32 or bf16
static __device__ __forceinline__ float loadf(const void* p, int i, bool f32) {
    if (f32) return ((const float*)p)[i];
    return bf2f(((const __hip_bfloat16*)p)[i]);
}

// ------------------------------------------------- runtime dtype detection
// flags[0] = 1 if edge_index is int64; flags[1] = 1 if float inputs are f32
__global__ __launch_bounds__(256) void detect_kernel(const unsigned* __restrict__ ew,
        const unsigned short* __restrict__ xw, int* __restrict__ flags) {
    __shared__ int s_odd, s_f32;
    int t = threadIdx.x;
    if (t == 0) { s_odd = 0; s_f32 = 0; }
    __syncthreads();
    unsigned acc = 0;
    for (int i = t; i < 2048; i += 256) acc |= ew[2 * i + 1];
    if (acc) atomicOr(&s_odd, 1);
    int f32ev = 0;
    for (int i = t; i < 4096; i += 256) {
        unsigned e = (xw[i] >> 7) & 0xFF;          // bf16 exponent field
        if (e >= 0xC0) f32ev = 1;                  // impossible for real bf16 data
    }
    if (f32ev) atomicOr(&s_f32, 1);
    __syncthreads();
    if (t == 0) { flags[0] = s_odd ? 0 : 1; flags[1] = s_f32; }
}

// ---------------------------------------------------------------- CSR build v2
// Two-level binned counting sort. R7's flat bucket_kernel had 105MB HBM
// writeback for a 6.4MB payload (each 64B ebuf line written by ~16 blocks on
// 8 non-coherent XCDs -> one writeback per 4B store). Here the fine scatter
// confines each block's writes to its own bin's ~16KB span -> 1x writeback.
// Bins: node >> 8 (256 nodes/bin); N <= 131072 assumed (N = 100000).

// decode helpers (inline, layout per flags[0])
static __device__ __forceinline__ int dec_src(const unsigned* ew, int E, bool i64, int e) {
    return i64 ? (int)ew[2 * (size_t)e] : (int)ew[e];
}
static __device__ __forceinline__ int dec_dst(const unsigned* ew, int E, bool i64, int e) {
    return i64 ? (int)ew[2 * (size_t)E + 2 * (size_t)e] : (int)ew[(size_t)E + e];
}

// (1) coarse histogram of dst over 512 bins (LDS-staged)
__global__ __launch_bounds__(256) void coarse_count(const unsigned* __restrict__ ew, int E,
        const int* __restrict__ flags, int* __restrict__ ccnt) {
    __shared__ int h[512];
    int tid = threadIdx.x;
    for (int i = tid; i < 512; i += 256) h[i] = 0;
    __syncthreads();
    bool i64 = flags[0] != 0;
    int base = blockIdx.x * 8192;
    int lim = min(base + 8192, E);
    for (int e = base + tid; e < lim; e += 256)
        atomicAdd(&h[dec_dst(ew, E, i64, e) >> 8], 1);
    __syncthreads();
    for (int i = tid; i < 512; i += 256) if (h[i]) atomicAdd(&ccnt[i], h[i]);
}

// (2) scan bins -> cbase (exclusive, cbase[NBINS]=E) and ccur (working cursor)
__global__ __launch_bounds__(256) void coarse_scan(const int* __restrict__ ccnt,
        int* __restrict__ cbase, int* __restrict__ ccur, int NBINS) {
    __shared__ int part[256];
    int t = threadIdx.x;
    int v0 = (2 * t     < NBINS) ? ccnt[2 * t]     : 0;
    int v1 = (2 * t + 1 < NBINS) ? ccnt[2 * t + 1] : 0;
    int sum = v0 + v1;
    part[t] = sum;
    __syncthreads();
    for (int off = 1; off < 256; off <<= 1) {
        int u = (t >= off) ? part[t - off] : 0;
        __syncthreads();
        part[t] += u;
        __syncthreads();
    }
    int run = part[t] - sum;
    if (2 * t < NBINS)     { cbase[2 * t] = run;     ccur[2 * t] = run; }
    run += v0;
    if (2 * t + 1 < NBINS) { cbase[2 * t + 1] = run; ccur[2 * t + 1] = run; }
    if (t == 255) cbase[NBINS] = part[255];
}

// (3) LDS-staged coarse scatter: pairs[] gets (src, dst&255) grouped by bin.
// Per block: 2048 edges staged in LDS ordered by bin, flushed with coalesced
// binary-search-indexed segment writes.
__global__ __launch_bounds__(256) void coarse_scatter(const unsigned* __restrict__ ew, int E,
        const int* __restrict__ flags, int* __restrict__ ccur,
        uint2* __restrict__ pairs, int NBINS) {
    __shared__ int hist[512];
    __shared__ int hscan[513];
    __shared__ int fbase[512];
    __shared__ int part[256];
    __shared__ uint2 stage[2048];
    int tid = threadIdx.x;
    bool i64 = flags[0] != 0;
    int base = blockIdx.x * 2048;
    int cnt = min(2048, E - base);
    for (int i = tid; i < 512; i += 256) hist[i] = 0;
    __syncthreads();
    int myb[8], myo[8], mys[8], myd[8];
    #pragma unroll
    for (int j = 0; j < 8; ++j) {
        int e = base + j * 256 + tid;
        myb[j] = -1;
        if (e < E) {
            mys[j] = dec_src(ew, E, i64, e);
            int d = dec_dst(ew, E, i64, e);
            myd[j] = d & 255;
            myb[j] = d >> 8;
            myo[j] = atomicAdd(&hist[myb[j]], 1);
        }
    }
    __syncthreads();
    // exclusive scan of hist[0..512) -> hscan
    {
        int v0 = hist[2 * tid], v1 = hist[2 * tid + 1];
        int sum = v0 + v1;
        part[tid] = sum;
        __syncthreads();
        for (int off = 1; off < 256; off <<= 1) {
            int u = (tid >= off) ? part[tid - off] : 0;
            __syncthreads();
            part[tid] += u;
            __syncthreads();
        }
        int run = part[tid] - sum;
        hscan[2 * tid] = run;
        hscan[2 * tid + 1] = run + v0;
        if (tid == 255) hscan[512] = part[255];
    }
    __syncthreads();
    #pragma unroll
    for (int j = 0; j < 8; ++j)
        if (myb[j] >= 0) {
            uint2 p; p.x = (unsigned)mys[j]; p.y = (unsigned)myd[j];
            stage[hscan[myb[j]] + myo[j]] = p;
        }
    for (int i = tid; i < NBINS; i += 256) {
        int c = hist[i];
        if (c) fbase[i] = atomicAdd(&ccur[i], c);
    }
    __syncthreads();
    for (int i = tid; i < cnt; i += 256) {
        int lo = 0, hi = NBINS;                 // largest b with hscan[b] <= i
        while (hi - lo > 1) {
            int mid = (lo + hi) >> 1;
            if (hscan[mid] <= i) lo = mid; else hi = mid;
        }
        pairs[(size_t)fbase[lo] + (i - hscan[lo])] = stage[i];
    }
}

// (4) per-bin degree histogram -> deg (coalesced write; replaces 1.6M global atomics)
__global__ __launch_bounds__(256) void bin_degree(const uint2* __restrict__ pairs,
        const int* __restrict__ cbase, int* __restrict__ deg, int N) {
    __shared__ int dl[256];
    int tid = threadIdx.x, b = blockIdx.x;
    dl[tid] = 0;
    __syncthreads();
    int s = cbase[b], e = cbase[b + 1];
    for (int i = s + tid; i < e; i += 256) atomicAdd(&dl[pairs[i].y], 1);
    __syncthreads();
    int node = (b << 8) + tid;
    if (node < N) deg[node] = dl[tid];
}

// (5) fine scatter: one block owns one bin's ebuf span (~16KB) -> no line sharing
__global__ __launch_bounds__(256) void bin_scatter(const uint2* __restrict__ pairs,
        const int* __restrict__ cbase, const int* __restrict__ rowptr,
        int* __restrict__ ebuf, int N) {
    __shared__ int cur[256];
    int tid = threadIdx.x, b = blockIdx.x;
    int node = (b << 8) + tid;
    cur[tid] = (node < N) ? rowptr[node] : 0;
    __syncthreads();
    int s = cbase[b], e = cbase[b + 1];
    for (int i = s + tid; i < e; i += 256) {
        uint2 p = pairs[i];
        int pos = atomicAdd(&cur[p.y], 1);
        ebuf[pos] = (int)p.x;
    }
}

// ---- 3-phase multi-block exclusive scan over deg (512 elements per block) ----
__global__ __launch_bounds__(256) void scan_phaseA(const int* __restrict__ deg,
        int* __restrict__ blocksum, int N) {
    __shared__ int red[256];
    int i0 = blockIdx.x * 512 + threadIdx.x * 2;
    int s = 0;
    if (i0 < N)     s += deg[i0];
    if (i0 + 1 < N) s += deg[i0 + 1];
    red[threadIdx.x] = s;
    __syncthreads();
    for (int off = 128; off; off >>= 1) {
        if (threadIdx.x < off) red[threadIdx.x] += red[threadIdx.x + off];
        __syncthreads();
    }
    if (threadIdx.x == 0) blocksum[blockIdx.x] = red[0];
}

__global__ __launch_bounds__(256) void scan_phaseB(int* __restrict__ blocksum, int NB,
        int* __restrict__ rowptr, int N) {
    __shared__ int part[256];
    int t = threadIdx.x;
    int v[4]; int sum = 0;
    #pragma unroll
    for (int j = 0; j < 4; ++j) {
        int i = 4 * t + j;
        v[j] = (i < NB) ? blocksum[i] : 0;
        sum += v[j];
    }
    part[t] = sum;
    __syncthreads();
    for (int off = 1; off < 256; off <<= 1) {
        int u = (t >= off) ? part[t - off] : 0;
        __syncthreads();
        part[t] += u;
        __syncthreads();
    }
    int run = part[t] - sum;   // exclusive prefix
    #pragma unroll
    for (int j = 0; j < 4; ++j) {
        int i = 4 * t + j;
        if (i < NB) blocksum[i] = run;
        run += v[j];
    }
    if (t == 255) rowptr[N] = part[255];
}

__global__ __launch_bounds__(256) void scan_phaseC(const int* __restrict__ deg,
        const int* __restrict__ blockoff, int* __restrict__ rowptr, int N) {
    __shared__ int part[256];
    int t = threadIdx.x;
    int i0 = blockIdx.x * 512 + 2 * t;
    int d0 = (i0 < N)     ? deg[i0]     : 0;
    int d1 = (i0 + 1 < N) ? deg[i0 + 1] : 0;
    int sum = d0 + d1;
    part[t] = sum;
    __syncthreads();
    for (int off = 1; off < 256; off <<= 1) {
        int u = (t >= off) ? part[t - off] : 0;
        __syncthreads();
        part[t] += u;
        __syncthreads();
    }
    int run = blockoff[blockIdx.x] + part[t] - sum;
    if (i0 < N)     rowptr[i0] = run;
    run += d0;
    if (i0 + 1 < N) rowptr[i0 + 1] = run;
}

// ------------------------------------------------------- weight pre-transpose
__global__ void transpose_kernel(const void* __restrict__ W,
        __hip_bfloat16* __restrict__ Wt, int rows, int cols, int ldt,
        const int* __restrict__ flags) {
    int idx = blockIdx.x * blockDim.x + threadIdx.x;
    if (idx < rows * cols) {
        int fi = idx / cols, fo = idx % cols;
        Wt[fo * ldt + fi] = __float2bfloat16(loadf(W, idx, flags[1] != 0));
    }
}

// --------------------------------------------------------------- MFMA GEMM v4
// Block = 64 nodes (4 waves x 16-node stripes); cols in phases of 64 staged
// into LDS fragment-contiguous. See R7 notes.
template<int KSTEPS>
__global__ __launch_bounds__(256) void gemm_v4(
        const void* __restrict__ X0, const void* __restrict__ X1, int K0, int xflag,
        const __hip_bfloat16* __restrict__ Wt, const void* __restrict__ bias,
        void* __restrict__ outp, int ldo, int out_f32, int M, int Ncols,
        const int* __restrict__ flags) {
    constexpr int K = KSTEPS * 32;
    constexpr int CH = K / 8;
    __shared__ short Wf[4 * KSTEPS * 64 * 8];
    bool pf = flags[1] != 0;
    bool xf32 = (xflag != 0) && pf;
    int tid = threadIdx.x;
    int wave = tid >> 6, lane = tid & 63;
    int quad = lane >> 4, r = lane & 15;
    int node = blockIdx.x * 64 + wave * 16 + r;
    int nodeL = min(node, M - 1);

    bf16x8 xf[KSTEPS];
    if (xf32) {
        #pragma unroll
        for (int ks = 0; ks < KSTEPS; ++ks) {
            int k = ks * 32 + quad * 8;
            const float* p = (k < K0)
                ? ((const float*)X0 + (size_t)nodeL * K0 + k)
                : ((const float*)X1 + (size_t)nodeL * (K - K0) + (k - K0));
            float4 a = *(const float4*)p;
            float4 b = *(const float4*)(p + 4);
            bf16x8 t;
            t[0] = f2bs(a.x); t[1] = f2bs(a.y); t[2] = f2bs(a.z); t[3] = f2bs(a.w);
            t[4] = f2bs(b.x); t[5] = f2bs(b.y); t[6] = f2bs(b.z); t[7] = f2bs(b.w);
            xf[ks] = t;
        }
    } else {
        #pragma unroll
        for (int ks = 0; ks < KSTEPS; ++ks) {
            int k = ks * 32 + quad * 8;
            const __hip_bfloat16* p = (k < K0)
                ? ((const __hip_bfloat16*)X0 + (size_t)nodeL * K0 + k)
                : ((const __hip_bfloat16*)X1 + (size_t)nodeL * (K - K0) + (k - K0));
            xf[ks] = *(const bf16x8*)p;
        }
    }

    int nphases = Ncols >> 6;
    for (int p = 0; p < nphases; ++p) {
        if (p) __syncthreads();
        #pragma unroll
        for (int i = 0; i < KSTEPS; ++i) {
            int idx = i * 256 + tid;
            int row_l = idx / CH, c = idx % CH;
            uint4 v = *(const uint4*)((const short*)Wt + (size_t)(p * 64 + row_l) * K + c * 8);
            int ftl = row_l >> 4, rr = row_l & 15;
            int ks = c >> 2, q = c & 3;
            *(uint4*)(Wf + (size_t)(((ftl * KSTEPS + ks) * 64) + q * 16 + rr) * 8) = v;
        }
        __syncthreads();
        #pragma unroll
        for (int ftl = 0; ftl < 4; ++ftl) {
            f32x4 acc = {0.f, 0.f, 0.f, 0.f};
            #pragma unroll
            for (int ks = 0; ks < KSTEPS; ++ks) {
                bf16x8 wf = *(const bf16x8*)(Wf + (size_t)((ftl * KSTEPS + ks) * 64 + lane) * 8);
                acc = __builtin_amdgcn_mfma_f32_16x16x32_bf16(wf, xf[ks], acc, 0, 0, 0);
            }
            int fo = p * 64 + ftl * 16 + quad * 4;
            float b0 = 0.f, b1 = 0.f, b2 = 0.f, b3 = 0.f;
            if (bias) {
                b0 = loadf(bias, fo + 0, pf); b1 = loadf(bias, fo + 1, pf);
                b2 = loadf(bias, fo + 2, pf); b3 = loadf(bias, fo + 3, pf);
            }
            if (node < M) {
                if (out_f32) {
                    float4 res;
                    res.x = acc[0] + b0; res.y = acc[1] + b1;
                    res.z = acc[2] + b2; res.w = acc[3] + b3;
                    *(float4*)((float*)outp + (size_t)node * ldo + fo) = res;
                } else {
                    short4 res;
                    res.x = f2bs(acc[0] + b0); res.y = f2bs(acc[1] + b1);
                    res.z = f2bs(acc[2] + b2); res.w = f2bs(acc[3] + b3);
                    *(short4*)((short*)outp + (size_t)node * ldo + fo) = res;
                }
            }
        }
    }
}

// --------------------------------------- fused mean-agg + bias + lin_r + LN + ReLU
__global__ __launch_bounds__(256) void agg_ln_relu(
        const __hip_bfloat16* __restrict__ yz, const int* __restrict__ rowptr,
        const int* __restrict__ ebuf,
        const void* __restrict__ bn, const void* __restrict__ g,
        const void* __restrict__ be, __hip_bfloat16* __restrict__ hout, int N,
        const int* __restrict__ flags) {
    int node = (blockIdx.x * blockDim.x + threadIdx.x) >> 6;
    if (node >= N) return;
    node = __builtin_amdgcn_readfirstlane(node);
    bool pf = flags[1] != 0;
    int lane = threadIdx.x & 63;
    int f = lane * 2;
    const short* yzs = (const short*)yz;
    int start = rowptr[node], end = rowptr[node + 1];
    float a0 = 0.f, a1 = 0.f;
    int i = start;
    for (; i + 8 <= end; i += 8) {
        int n0 = ebuf[i + 0], n1 = ebuf[i + 1], n2 = ebuf[i + 2], n3 = ebuf[i + 3];
        int n4 = ebuf[i + 4], n5 = ebuf[i + 5], n6 = ebuf[i + 6], n7 = ebuf[i + 7];
        short2 t0 = *(const short2*)(yzs + (size_t)n0 * 256 + f);
        short2 t1 = *(const short2*)(yzs + (size_t)n1 * 256 + f);
        short2 t2 = *(const short2*)(yzs + (size_t)n2 * 256 + f);
        short2 t3 = *(const short2*)(yzs + (size_t)n3 * 256 + f);
        short2 t4 = *(const short2*)(yzs + (size_t)n4 * 256 + f);
        short2 t5 = *(const short2*)(yzs + (size_t)n5 * 256 + f);
        short2 t6 = *(const short2*)(yzs + (size_t)n6 * 256 + f);
        short2 t7 = *(const short2*)(yzs + (size_t)n7 * 256 + f);
        a0 += bs2f(t0.x) + bs2f(t1.x) + bs2f(t2.x) + bs2f(t3.x)
            + bs2f(t4.x) + bs2f(t5.x) + bs2f(t6.x) + bs2f(t7.x);
        a1 += bs2f(t0.y) + bs2f(t1.y) + bs2f(t2.y) + bs2f(t3.y)
            + bs2f(t4.y) + bs2f(t5.y) + bs2f(t6.y) + bs2f(t7.y);
    }
    for (; i + 2 <= end; i += 2) {
        int n0 = ebuf[i + 0], n1 = ebuf[i + 1];
        short2 t0 = *(const short2*)(yzs + (size_t)n0 * 256 + f);
        short2 t1 = *(const short2*)(yzs + (size_t)n1 * 256 + f);
        a0 += bs2f(t0.x) + bs2f(t1.x);
        a1 += bs2f(t0.y) + bs2f(t1.y);
    }
    if (i < end) {
        int n0 = ebuf[i];
        short2 t0 = *(const short2*)(yzs + (size_t)n0 * 256 + f);
        a0 += bs2f(t0.x);
        a1 += bs2f(t0.y);
    }
    float inv = 1.f / fmaxf((float)(end - start), 1.f);
    short2 zt = *(const short2*)(yzs + (size_t)node * 256 + 128 + f);
    float v0 = a0 * inv + loadf(bn, f, pf)     + bs2f(zt.x);
    float v1 = a1 * inv + loadf(bn, f + 1, pf) + bs2f(zt.y);
    float s = v0 + v1;
    #pragma unroll
    for (int off = 32; off > 0; off >>= 1) s += __shfl_xor(s, off, 64);
    float mu = s * (1.f / 128.f);
    float d0 = v0 - mu, d1 = v1 - mu;
    float q = d0 * d0 + d1 * d1;
    #pragma unroll
    for (int off = 32; off > 0; off >>= 1) q += __shfl_xor(q, off, 64);
    float rstd = rsqrtf(q * (1.f / 128.f) + 1e-5f);
    float o0 = fmaxf(d0 * rstd * loadf(g, f, pf)     + loadf(be, f, pf),     0.f);
    float o1 = fmaxf(d1 * rstd * loadf(g, f + 1, pf) + loadf(be, f + 1, pf), 0.f);
    short* hp = (short*)hout + (size_t)node * 128 + f;
    hp[0] = f2bs(o0);
    hp[1] = f2bs(o1);
}

// ------------------------------------------------------------- MLP head
__global__ __launch_bounds__(256) void head_kernel(
        const float* __restrict__ feats, const void* __restrict__ Wh1,
        const void* __restrict__ bh1, const void* __restrict__ Wh2,
        const void* __restrict__ bh2, void* __restrict__ outp, int N,
        const int* __restrict__ flags) {
    __shared__ float sfe[8 * 128];
    __shared__ float shid[8 * 32];
    bool pf = flags[1] != 0;
    int nb = blockIdx.x * 8;
    int tid = threadIdx.x;
    {
        int i = tid * 4;
        int gnode = nb + (i >> 7);
        float4 v = make_float4(0.f, 0.f, 0.f, 0.f);
        if (gnode < N) v = *(const float4*)(feats + (size_t)gnode * 128 + (i & 127));
        *(float4*)(sfe + i) = v;
    }
    __syncthreads();
    {
        int nloc = tid >> 5, col = tid & 31;
        float acc = loadf(bh1, col, pf);
        const float* fr = sfe + nloc * 128;
        #pragma unroll 8
        for (int k = 0; k < 128; ++k) acc += fr[k] * loadf(Wh1, k * 32 + col, pf);
        shid[nloc * 32 + col] = fmaxf(acc, 0.f);
    }
    __syncthreads();
    if (tid < 128) {
        int nloc = tid >> 4, col = tid & 15;
        int gnode = nb + nloc;
        if (gnode < N) {
            float acc = loadf(bh2, col, pf);
            const float* hr = shid + nloc * 32;
            #pragma unroll
            for (int k = 0; k < 32; ++k) acc += hr[k] * loadf(Wh2, k * 16 + col, pf);
            if (pf) ((float*)outp)[(size_t)gnode * 16 + col] = acc;
            else    ((__hip_bfloat16*)outp)[(size_t)gnode * 16 + col] = __float2bfloat16(acc);
        }
    }
}

// ---------------------------------------------------------------- launcher
extern "C" void kernel_launch(void* const* d_in, const int* in_sizes, int n_in,
                              void* d_out, int out_size, void* d_ws, size_t ws_size,
                              hipStream_t stream) {
    const void* x    = d_in[0];
    const unsigned* ei = (const unsigned*)d_in[1];
    const void* Wnl0 = d_in[2];
    const void* bnl0 = d_in[3];
    const void* Wr0  = d_in[4];
    const void* Wnl1 = d_in[5];
    const void* bnl1 = d_in[6];
    const void* Wr1  = d_in[7];
    const void* g0   = d_in[8];
    const void* be0  = d_in[9];
    const void* g1   = d_in[10];
    const void* be1  = d_in[11];
    const void* Wjk  = d_in[12];
    const void* bjk  = d_in[13];
    const void* Wh1  = d_in[14];
    const void* bh1  = d_in[15];
    const void* Wh2  = d_in[16];
    const void* bh2  = d_in[17];

    const int N = in_sizes[0] / 256;
    const int E = in_sizes[1] / 2;
    const int NBINS = (N + 255) >> 8;

    char* ws = (char*)d_ws;
    size_t off = 0;
    auto alloc = [&](size_t bytes) -> void* {
        void* p = ws + off;
        off = (off + bytes + 255) & ~(size_t)255;
        return p;
    };
    int* flags  = (int*)alloc(256);
    int* rowptr = (int*)alloc((size_t)(N + 1) * 4);
    int* deg    = (int*)alloc((size_t)N * 4);
    int* ebuf   = (int*)alloc((size_t)E * 4);
    int* blocksum = (int*)alloc(1024 * 4);
    int* ccnt   = (int*)alloc(512 * 4);
    int* cbase  = (int*)alloc(513 * 4);
    int* ccur   = (int*)alloc(512 * 4);
    uint2* pairs = (uint2*)alloc((size_t)E * 8);
    __hip_bfloat16* Wt0  = (__hip_bfloat16*)alloc(256 * 256 * 2);
    __hip_bfloat16* Wt1  = (__hip_bfloat16*)alloc(256 * 128 * 2);
    __hip_bfloat16* Wtjk = (__hip_bfloat16*)alloc(128 * 256 * 2);
    __hip_bfloat16* yz = (__hip_bfloat16*)alloc((size_t)N * 256 * 2);
    __hip_bfloat16* h0 = (__hip_bfloat16*)alloc((size_t)N * 128 * 2);
    __hip_bfloat16* h1 = (__hip_bfloat16*)alloc((size_t)N * 128 * 2);
    float* feats = (float*)yz;   // yz dead after second agg; same byte size

    // dtype detection
    detect_kernel<<<1, 256, 0, stream>>>(ei, (const unsigned short*)x, flags);

    // CSR build v2 (two-level binned counting sort)
    (void)hipMemsetAsync(ccnt, 0, 512 * 4, stream);
    coarse_count<<<(E + 8191) / 8192, 256, 0, stream>>>(ei, E, flags, ccnt);
    coarse_scan<<<1, 256, 0, stream>>>(ccnt, cbase, ccur, NBINS);
    coarse_scatter<<<(E + 2047) / 2048, 256, 0, stream>>>(ei, E, flags, ccur, pairs, NBINS);
    bin_degree<<<NBINS, 256, 0, stream>>>(pairs, cbase, deg, N);
    int NB = (N + 511) / 512;
    scan_phaseA<<<NB, 256, 0, stream>>>(deg, blocksum, N);
    scan_phaseB<<<1, 256, 0, stream>>>(blocksum, NB, rowptr, N);
    scan_phaseC<<<NB, 256, 0, stream>>>(deg, blocksum, rowptr, N);
    bin_scatter<<<NBINS, 256, 0, stream>>>(pairs, cbase, rowptr, ebuf, N);

    // Weight transposes
    transpose_kernel<<<(256 * 128 + 255) / 256, 256, 0, stream>>>(Wnl0, Wt0, 256, 128, 256, flags);
    transpose_kernel<<<(256 * 128 + 255) / 256, 256, 0, stream>>>(Wr0,  Wt0 + 128 * 256, 256, 128, 256, flags);
    transpose_kernel<<<(128 * 128 + 255) / 256, 256, 0, stream>>>(Wnl1, Wt1, 128, 128, 128, flags);
    transpose_kernel<<<(128 * 128 + 255) / 256, 256, 0, stream>>>(Wr1,  Wt1 + 128 * 128, 128, 128, 128, flags);
    transpose_kernel<<<(256 * 128 + 255) / 256, 256, 0, stream>>>(Wjk,  Wtjk, 256, 128, 256, flags);

    int gblocks = (N + 63) / 64;
    int ablocks = (int)(((size_t)N * 64 + 255) / 256);

    // layer 0: project (y0 = x@Wnl0, z0 = x@Wr0) -> agg+LN+ReLU -> h0
    gemm_v4<8><<<gblocks, 256, 0, stream>>>(x, x, 256, 1, Wt0, nullptr, yz, 256, 0, N, 256, flags);
    agg_ln_relu<<<ablocks, 256, 0, stream>>>(yz, rowptr, ebuf, bnl0, g0, be0, h0, N, flags);

    // layer 1 (K=128)
    gemm_v4<4><<<gblocks, 256, 0, stream>>>(h0, h0, 128, 0, Wt1, nullptr, yz, 256, 0, N, 256, flags);
    agg_ln_relu<<<ablocks, 256, 0, stream>>>(yz, rowptr, ebuf, bnl1, g1, be1, h1, N, flags);

    // JK: feats = [h0|h1] @ Wjk + bjk   (K split 128/128), f32 output
    gemm_v4<8><<<gblocks, 256, 0, stream>>>(h0, h1, 128, 0, Wtjk, bjk, feats, 128, 1, N, 128, flags);

    // MLP head
    head_kernel<<<(N + 7) / 8, 256, 0, stream>>>(feats, Wh1, bh1, Wh2, bh2, d_out, N, flags);
}

// Round 9
// 573.578 us; speedup vs baseline: 2.1707x; 1.0261x over previous
//
#include <hip/hip_runtime.h>
#include <hip/hip_bf16.h>

typedef __attribute__((ext_vector_type(8))) short bf16x8;   // 8 bf16 = 4 VGPRs
typedef __attribute__((ext_vector_type(4))) float f32x4;    // 4 f32 acc

static __device__ __forceinline__ float bf2f(__hip_bfloat16 v) { return __bfloat162float(v); }

static __device__ __forceinline__ float bs2f(short s) {
    unsigned u = ((unsigned)(unsigned short)s) << 16;
    float f; __builtin_memcpy(&f, &u, 4); return f;
}
static __device__ __forceinline__ short f2bs(float v) {
    __hip_bfloat16 b = __float2bfloat16(v);
    short s; __builtin_memcpy(&s, &b, 2); return s;
}
// read element i of a float array that is either f32 or bf16
static __device__ __forceinline__ float loadf(const void* p, int i, bool f32) {
    if (f32) return ((const float*)p)[i];
    return bf2f(((const __hip_bfloat16*)p)[i]);
}

// ------------------------------------------------- runtime dtype detection
// flags[0] = 1 if edge_index is int64; flags[1] = 1 if float inputs are f32
__global__ __launch_bounds__(256) void detect_kernel(const unsigned* __restrict__ ew,
        const unsigned short* __restrict__ xw, int* __restrict__ flags) {
    __shared__ int s_odd, s_f32;
    int t = threadIdx.x;
    if (t == 0) { s_odd = 0; s_f32 = 0; }
    __syncthreads();
    unsigned acc = 0;
    for (int i = t; i < 2048; i += 256) acc |= ew[2 * i + 1];
    if (acc) atomicOr(&s_odd, 1);
    int f32ev = 0;
    for (int i = t; i < 4096; i += 256) {
        unsigned e = (xw[i] >> 7) & 0xFF;          // bf16 exponent field
        if (e >= 0xC0) f32ev = 1;                  // impossible for real bf16 data
    }
    if (f32ev) atomicOr(&s_f32, 1);
    __syncthreads();
    if (t == 0) { flags[0] = s_odd ? 0 : 1; flags[1] = s_f32; }
}

// ---------------------------------------------------------------- CSR build v2
// Two-level binned counting sort (R8): fine scatter confines each block's
// writes to its own bin's span -> ~1x HBM writeback (R7 flat scatter was 16x).

static __device__ __forceinline__ int dec_src(const unsigned* ew, int E, bool i64, int e) {
    return i64 ? (int)ew[2 * (size_t)e] : (int)ew[e];
}
static __device__ __forceinline__ int dec_dst(const unsigned* ew, int E, bool i64, int e) {
    return i64 ? (int)ew[2 * (size_t)E + 2 * (size_t)e] : (int)ew[(size_t)E + e];
}

__global__ __launch_bounds__(256) void coarse_count(const unsigned* __restrict__ ew, int E,
        const int* __restrict__ flags, int* __restrict__ ccnt) {
    __shared__ int h[512];
    int tid = threadIdx.x;
    for (int i = tid; i < 512; i += 256) h[i] = 0;
    __syncthreads();
    bool i64 = flags[0] != 0;
    int base = blockIdx.x * 8192;
    int lim = min(base + 8192, E);
    for (int e = base + tid; e < lim; e += 256)
        atomicAdd(&h[dec_dst(ew, E, i64, e) >> 8], 1);
    __syncthreads();
    for (int i = tid; i < 512; i += 256) if (h[i]) atomicAdd(&ccnt[i], h[i]);
}

__global__ __launch_bounds__(256) void coarse_scan(const int* __restrict__ ccnt,
        int* __restrict__ cbase, int* __restrict__ ccur, int NBINS) {
    __shared__ int part[256];
    int t = threadIdx.x;
    int v0 = (2 * t     < NBINS) ? ccnt[2 * t]     : 0;
    int v1 = (2 * t + 1 < NBINS) ? ccnt[2 * t + 1] : 0;
    int sum = v0 + v1;
    part[t] = sum;
    __syncthreads();
    for (int off = 1; off < 256; off <<= 1) {
        int u = (t >= off) ? part[t - off] : 0;
        __syncthreads();
        part[t] += u;
        __syncthreads();
    }
    int run = part[t] - sum;
    if (2 * t < NBINS)     { cbase[2 * t] = run;     ccur[2 * t] = run; }
    run += v0;
    if (2 * t + 1 < NBINS) { cbase[2 * t + 1] = run; ccur[2 * t + 1] = run; }
    if (t == 255) cbase[NBINS] = part[255];
}

__global__ __launch_bounds__(256) void coarse_scatter(const unsigned* __restrict__ ew, int E,
        const int* __restrict__ flags, int* __restrict__ ccur,
        uint2* __restrict__ pairs, int NBINS) {
    __shared__ int hist[512];
    __shared__ int hscan[513];
    __shared__ int fbase[512];
    __shared__ int part[256];
    __shared__ uint2 stage[2048];
    int tid = threadIdx.x;
    bool i64 = flags[0] != 0;
    int base = blockIdx.x * 2048;
    int cnt = min(2048, E - base);
    for (int i = tid; i < 512; i += 256) hist[i] = 0;
    __syncthreads();
    int myb[8], myo[8], mys[8], myd[8];
    #pragma unroll
    for (int j = 0; j < 8; ++j) {
        int e = base + j * 256 + tid;
        myb[j] = -1;
        if (e < E) {
            mys[j] = dec_src(ew, E, i64, e);
            int d = dec_dst(ew, E, i64, e);
            myd[j] = d & 255;
            myb[j] = d >> 8;
            myo[j] = atomicAdd(&hist[myb[j]], 1);
        }
    }
    __syncthreads();
    {
        int v0 = hist[2 * tid], v1 = hist[2 * tid + 1];
        int sum = v0 + v1;
        part[tid] = sum;
        __syncthreads();
        for (int off = 1; off < 256; off <<= 1) {
            int u = (tid >= off) ? part[tid - off] : 0;
            __syncthreads();
            part[tid] += u;
            __syncthreads();
        }
        int run = part[tid] - sum;
        hscan[2 * tid] = run;
        hscan[2 * tid + 1] = run + v0;
        if (tid == 255) hscan[512] = part[255];
    }
    __syncthreads();
    #pragma unroll
    for (int j = 0; j < 8; ++j)
        if (myb[j] >= 0) {
            uint2 p; p.x = (unsigned)mys[j]; p.y = (unsigned)myd[j];
            stage[hscan[myb[j]] + myo[j]] = p;
        }
    for (int i = tid; i < NBINS; i += 256) {
        int c = hist[i];
        if (c) fbase[i] = atomicAdd(&ccur[i], c);
    }
    __syncthreads();
    for (int i = tid; i < cnt; i += 256) {
        int lo = 0, hi = NBINS;
        while (hi - lo > 1) {
            int mid = (lo + hi) >> 1;
            if (hscan[mid] <= i) lo = mid; else hi = mid;
        }
        pairs[(size_t)fbase[lo] + (i - hscan[lo])] = stage[i];
    }
}

__global__ __launch_bounds__(256) void bin_degree(const uint2* __restrict__ pairs,
        const int* __restrict__ cbase, int* __restrict__ deg, int N) {
    __shared__ int dl[256];
    int tid = threadIdx.x, b = blockIdx.x;
    dl[tid] = 0;
    __syncthreads();
    int s = cbase[b], e = cbase[b + 1];
    for (int i = s + tid; i < e; i += 256) atomicAdd(&dl[pairs[i].y], 1);
    __syncthreads();
    int node = (b << 8) + tid;
    if (node < N) deg[node] = dl[tid];
}

__global__ __launch_bounds__(256) void bin_scatter(const uint2* __restrict__ pairs,
        const int* __restrict__ cbase, const int* __restrict__ rowptr,
        int* __restrict__ ebuf, int N) {
    __shared__ int cur[256];
    int tid = threadIdx.x, b = blockIdx.x;
    int node = (b << 8) + tid;
    cur[tid] = (node < N) ? rowptr[node] : 0;
    __syncthreads();
    int s = cbase[b], e = cbase[b + 1];
    for (int i = s + tid; i < e; i += 256) {
        uint2 p = pairs[i];
        int pos = atomicAdd(&cur[p.y], 1);
        ebuf[pos] = (int)p.x;
    }
}

// ---- 3-phase multi-block exclusive scan over deg ----
__global__ __launch_bounds__(256) void scan_phaseA(const int* __restrict__ deg,
        int* __restrict__ blocksum, int N) {
    __shared__ int red[256];
    int i0 = blockIdx.x * 512 + threadIdx.x * 2;
    int s = 0;
    if (i0 < N)     s += deg[i0];
    if (i0 + 1 < N) s += deg[i0 + 1];
    red[threadIdx.x] = s;
    __syncthreads();
    for (int off = 128; off; off >>= 1) {
        if (threadIdx.x < off) red[threadIdx.x] += red[threadIdx.x + off];
        __syncthreads();
    }
    if (threadIdx.x == 0) blocksum[blockIdx.x] = red[0];
}

__global__ __launch_bounds__(256) void scan_phaseB(int* __restrict__ blocksum, int NB,
        int* __restrict__ rowptr, int N) {
    __shared__ int part[256];
    int t = threadIdx.x;
    int v[4]; int sum = 0;
    #pragma unroll
    for (int j = 0; j < 4; ++j) {
        int i = 4 * t + j;
        v[j] = (i < NB) ? blocksum[i] : 0;
        sum += v[j];
    }
    part[t] = sum;
    __syncthreads();
    for (int off = 1; off < 256; off <<= 1) {
        int u = (t >= off) ? part[t - off] : 0;
        __syncthreads();
        part[t] += u;
        __syncthreads();
    }
    int run = part[t] - sum;
    #pragma unroll
    for (int j = 0; j < 4; ++j) {
        int i = 4 * t + j;
        if (i < NB) blocksum[i] = run;
        run += v[j];
    }
    if (t == 255) rowptr[N] = part[255];
}

__global__ __launch_bounds__(256) void scan_phaseC(const int* __restrict__ deg,
        const int* __restrict__ blockoff, int* __restrict__ rowptr, int N) {
    __shared__ int part[256];
    int t = threadIdx.x;
    int i0 = blockIdx.x * 512 + 2 * t;
    int d0 = (i0 < N)     ? deg[i0]     : 0;
    int d1 = (i0 + 1 < N) ? deg[i0 + 1] : 0;
    int sum = d0 + d1;
    part[t] = sum;
    __syncthreads();
    for (int off = 1; off < 256; off <<= 1) {
        int u = (t >= off) ? part[t - off] : 0;
        __syncthreads();
        part[t] += u;
        __syncthreads();
    }
    int run = blockoff[blockIdx.x] + part[t] - sum;
    if (i0 < N)     rowptr[i0] = run;
    run += d0;
    if (i0 + 1 < N) rowptr[i0 + 1] = run;
}

// ------------------------------------------------------- weight pre-transpose
__global__ void transpose_kernel(const void* __restrict__ W,
        __hip_bfloat16* __restrict__ Wt, int rows, int cols, int ldt,
        const int* __restrict__ flags) {
    int idx = blockIdx.x * blockDim.x + threadIdx.x;
    if (idx < rows * cols) {
        int fi = idx / cols, fo = idx % cols;
        Wt[fo * ldt + fi] = __float2bfloat16(loadf(W, idx, flags[1] != 0));
    }
}

// --------------------------------------------------------------- MFMA GEMM v5
// Block = 128 nodes (8 waves x 16-node stripes), 512 threads; cols in phases
// of 64 staged into LDS. XOR-swizzled layout: chunk (q*16+rr)^ks in segment
// (ftl,ks); reader uses lane^ks. Kills R8's full-wave same-bank staging
// conflicts (SQ_LDS_BANK_CONFLICT 1.12e7/dispatch: write residue chunk%8 was
// rr%8 for all 32 lanes of a half-wave -> 4x LDS stall). 128-node blocks also
// halve per-node W staging (R8 re-staged 128KB W per 64 nodes) and reach
// 4 blocks/CU = 32 waves (100% wave occupancy; was 35%).
template<int KSTEPS>
__global__ __launch_bounds__(512) void gemm_v5(
        const void* __restrict__ X0, const void* __restrict__ X1, int K0, int xflag,
        const __hip_bfloat16* __restrict__ Wt, const void* __restrict__ bias,
        void* __restrict__ outp, int ldo, int out_f32, int M, int Ncols,
        const int* __restrict__ flags) {
    constexpr int K = KSTEPS * 32;
    constexpr int CH = K / 8;              // 16B chunks per W row
    constexpr int SITERS = KSTEPS / 2;     // 64*CH/512 staging iterations
    __shared__ short Wf[4 * KSTEPS * 64 * 8];   // 32KB @ K=256
    bool pf = flags[1] != 0;
    bool xf32 = (xflag != 0) && pf;
    int tid = threadIdx.x;
    int wave = tid >> 6, lane = tid & 63;
    int quad = lane >> 4, r = lane & 15;
    int node = blockIdx.x * 128 + wave * 16 + r;
    int nodeL = min(node, M - 1);

    bf16x8 xf[KSTEPS];
    if (xf32) {
        #pragma unroll
        for (int ks = 0; ks < KSTEPS; ++ks) {
            int k = ks * 32 + quad * 8;
            const float* p = (k < K0)
                ? ((const float*)X0 + (size_t)nodeL * K0 + k)
                : ((const float*)X1 + (size_t)nodeL * (K - K0) + (k - K0));
            float4 a = *(const float4*)p;
            float4 b = *(const float4*)(p + 4);
            bf16x8 t;
            t[0] = f2bs(a.x); t[1] = f2bs(a.y); t[2] = f2bs(a.z); t[3] = f2bs(a.w);
            t[4] = f2bs(b.x); t[5] = f2bs(b.y); t[6] = f2bs(b.z); t[7] = f2bs(b.w);
            xf[ks] = t;
        }
    } else {
        #pragma unroll
        for (int ks = 0; ks < KSTEPS; ++ks) {
            int k = ks * 32 + quad * 8;
            const __hip_bfloat16* p = (k < K0)
                ? ((const __hip_bfloat16*)X0 + (size_t)nodeL * K0 + k)
                : ((const __hip_bfloat16*)X1 + (size_t)nodeL * (K - K0) + (k - K0));
            xf[ks] = *(const bf16x8*)p;
        }
    }

    int nphases = Ncols >> 6;              // 64 cols per phase
    for (int p = 0; p < nphases; ++p) {
        if (p) __syncthreads();
        // ---- stage 64 W rows into swizzled fragment layout ----
        #pragma unroll
        for (int i = 0; i < SITERS; ++i) {
            int idx = i * 512 + tid;
            int row_l = idx / CH, c = idx % CH;     // consecutive tid -> consecutive c (coalesced)
            uint4 v = *(const uint4*)((const short*)Wt + (size_t)(p * 64 + row_l) * K + c * 8);
            int ftl = row_l >> 4, rr = row_l & 15;
            int ks = c >> 2, q = c & 3;
            int chunk = ((q * 16 + rr) ^ ks);       // XOR swizzle: spreads chunk%8 across bank groups
            *(uint4*)(Wf + (size_t)(((ftl * KSTEPS + ks) * 64) + chunk) * 8) = v;
        }
        __syncthreads();
        // ---- compute: 4 independent ftile chains ----
        #pragma unroll
        for (int ftl = 0; ftl < 4; ++ftl) {
            f32x4 acc = {0.f, 0.f, 0.f, 0.f};
            #pragma unroll
            for (int ks = 0; ks < KSTEPS; ++ks) {
                bf16x8 wf = *(const bf16x8*)(Wf + (size_t)((ftl * KSTEPS + ks) * 64 + (lane ^ ks)) * 8);
                acc = __builtin_amdgcn_mfma_f32_16x16x32_bf16(wf, xf[ks], acc, 0, 0, 0);
            }
            int fo = p * 64 + ftl * 16 + quad * 4;
            float b0 = 0.f, b1 = 0.f, b2 = 0.f, b3 = 0.f;
            if (bias) {
                b0 = loadf(bias, fo + 0, pf); b1 = loadf(bias, fo + 1, pf);
                b2 = loadf(bias, fo + 2, pf); b3 = loadf(bias, fo + 3, pf);
            }
            if (node < M) {
                if (out_f32) {
                    float4 res;
                    res.x = acc[0] + b0; res.y = acc[1] + b1;
                    res.z = acc[2] + b2; res.w = acc[3] + b3;
                    *(float4*)((float*)outp + (size_t)node * ldo + fo) = res;
                } else {
                    short4 res;
                    res.x = f2bs(acc[0] + b0); res.y = f2bs(acc[1] + b1);
                    res.z = f2bs(acc[2] + b2); res.w = f2bs(acc[3] + b3);
                    *(short4*)((short*)outp + (size_t)node * ldo + fo) = res;
                }
            }
        }
    }
}

// --------------------------------------- fused mean-agg + bias + lin_r + LN + ReLU
__global__ __launch_bounds__(256) void agg_ln_relu(
        const __hip_bfloat16* __restrict__ yz, const int* __restrict__ rowptr,
        const int* __restrict__ ebuf,
        const void* __restrict__ bn, const void* __restrict__ g,
        const void* __restrict__ be, __hip_bfloat16* __restrict__ hout, int N,
        const int* __restrict__ flags) {
    int node = (blockIdx.x * blockDim.x + threadIdx.x) >> 6;
    if (node >= N) return;
    node = __builtin_amdgcn_readfirstlane(node);
    bool pf = flags[1] != 0;
    int lane = threadIdx.x & 63;
    int f = lane * 2;
    const short* yzs = (const short*)yz;
    int start = rowptr[node], end = rowptr[node + 1];
    float a0 = 0.f, a1 = 0.f;
    int i = start;
    for (; i + 8 <= end; i += 8) {
        int n0 = ebuf[i + 0], n1 = ebuf[i + 1], n2 = ebuf[i + 2], n3 = ebuf[i + 3];
        int n4 = ebuf[i + 4], n5 = ebuf[i + 5], n6 = ebuf[i + 6], n7 = ebuf[i + 7];
        short2 t0 = *(const short2*)(yzs + (size_t)n0 * 256 + f);
        short2 t1 = *(const short2*)(yzs + (size_t)n1 * 256 + f);
        short2 t2 = *(const short2*)(yzs + (size_t)n2 * 256 + f);
        short2 t3 = *(const short2*)(yzs + (size_t)n3 * 256 + f);
        short2 t4 = *(const short2*)(yzs + (size_t)n4 * 256 + f);
        short2 t5 = *(const short2*)(yzs + (size_t)n5 * 256 + f);
        short2 t6 = *(const short2*)(yzs + (size_t)n6 * 256 + f);
        short2 t7 = *(const short2*)(yzs + (size_t)n7 * 256 + f);
        a0 += bs2f(t0.x) + bs2f(t1.x) + bs2f(t2.x) + bs2f(t3.x)
            + bs2f(t4.x) + bs2f(t5.x) + bs2f(t6.x) + bs2f(t7.x);
        a1 += bs2f(t0.y) + bs2f(t1.y) + bs2f(t2.y) + bs2f(t3.y)
            + bs2f(t4.y) + bs2f(t5.y) + bs2f(t6.y) + bs2f(t7.y);
    }
    for (; i + 2 <= end; i += 2) {
        int n0 = ebuf[i + 0], n1 = ebuf[i + 1];
        short2 t0 = *(const short2*)(yzs + (size_t)n0 * 256 + f);
        short2 t1 = *(const short2*)(yzs + (size_t)n1 * 256 + f);
        a0 += bs2f(t0.x) + bs2f(t1.x);
        a1 += bs2f(t0.y) + bs2f(t1.y);
    }
    if (i < end) {
        int n0 = ebuf[i];
        short2 t0 = *(const short2*)(yzs + (size_t)n0 * 256 + f);
        a0 += bs2f(t0.x);
        a1 += bs2f(t0.y);
    }
    float inv = 1.f / fmaxf((float)(end - start), 1.f);
    short2 zt = *(const short2*)(yzs + (size_t)node * 256 + 128 + f);
    float v0 = a0 * inv + loadf(bn, f, pf)     + bs2f(zt.x);
    float v1 = a1 * inv + loadf(bn, f + 1, pf) + bs2f(zt.y);
    float s = v0 + v1;
    #pragma unroll
    for (int off = 32; off > 0; off >>= 1) s += __shfl_xor(s, off, 64);
    float mu = s * (1.f / 128.f);
    float d0 = v0 - mu, d1 = v1 - mu;
    float q = d0 * d0 + d1 * d1;
    #pragma unroll
    for (int off = 32; off > 0; off >>= 1) q += __shfl_xor(q, off, 64);
    float rstd = rsqrtf(q * (1.f / 128.f) + 1e-5f);
    float o0 = fmaxf(d0 * rstd * loadf(g, f, pf)     + loadf(be, f, pf),     0.f);
    float o1 = fmaxf(d1 * rstd * loadf(g, f + 1, pf) + loadf(be, f + 1, pf), 0.f);
    short* hp = (short*)hout + (size_t)node * 128 + f;
    hp[0] = f2bs(o0);
    hp[1] = f2bs(o1);
}

// ------------------------------------------------------------- MLP head
__global__ __launch_bounds__(256) void head_kernel(
        const float* __restrict__ feats, const void* __restrict__ Wh1,
        const void* __restrict__ bh1, const void* __restrict__ Wh2,
        const void* __restrict__ bh2, void* __restrict__ outp, int N,
        const int* __restrict__ flags) {
    __shared__ float sfe[8 * 128];
    __shared__ float shid[8 * 32];
    bool pf = flags[1] != 0;
    int nb = blockIdx.x * 8;
    int tid = threadIdx.x;
    {
        int i = tid * 4;
        int gnode = nb + (i >> 7);
        float4 v = make_float4(0.f, 0.f, 0.f, 0.f);
        if (gnode < N) v = *(const float4*)(feats + (size_t)gnode * 128 + (i & 127));
        *(float4*)(sfe + i) = v;
    }
    __syncthreads();
    {
        int nloc = tid >> 5, col = tid & 31;
        float acc = loadf(bh1, col, pf);
        const float* fr = sfe + nloc * 128;
        #pragma unroll 8
        for (int k = 0; k < 128; ++k) acc += fr[k] * loadf(Wh1, k * 32 + col, pf);
        shid[nloc * 32 + col] = fmaxf(acc, 0.f);
    }
    __syncthreads();
    if (tid < 128) {
        int nloc = tid >> 4, col = tid & 15;
        int gnode = nb + nloc;
        if (gnode < N) {
            float acc = loadf(bh2, col, pf);
            const float* hr = shid + nloc * 32;
            #pragma unroll
            for (int k = 0; k < 32; ++k) acc += hr[k] * loadf(Wh2, k * 16 + col, pf);
            if (pf) ((float*)outp)[(size_t)gnode * 16 + col] = acc;
            else    ((__hip_bfloat16*)outp)[(size_t)gnode * 16 + col] = __float2bfloat16(acc);
        }
    }
}

// ---------------------------------------------------------------- launcher
extern "C" void kernel_launch(void* const* d_in, const int* in_sizes, int n_in,
                              void* d_out, int out_size, void* d_ws, size_t ws_size,
                              hipStream_t stream) {
    const void* x    = d_in[0];
    const unsigned* ei = (const unsigned*)d_in[1];
    const void* Wnl0 = d_in[2];
    const void* bnl0 = d_in[3];
    const void* Wr0  = d_in[4];
    const void* Wnl1 = d_in[5];
    const void* bnl1 = d_in[6];
    const void* Wr1  = d_in[7];
    const void* g0   = d_in[8];
    const void* be0  = d_in[9];
    const void* g1   = d_in[10];
    const void* be1  = d_in[11];
    const void* Wjk  = d_in[12];
    const void* bjk  = d_in[13];
    const void* Wh1  = d_in[14];
    const void* bh1  = d_in[15];
    const void* Wh2  = d_in[16];
    const void* bh2  = d_in[17];

    const int N = in_sizes[0] / 256;
    const int E = in_sizes[1] / 2;
    const int NBINS = (N + 255) >> 8;

    char* ws = (char*)d_ws;
    size_t off = 0;
    auto alloc = [&](size_t bytes) -> void* {
        void* p = ws + off;
        off = (off + bytes + 255) & ~(size_t)255;
        return p;
    };
    int* flags  = (int*)alloc(256);
    int* rowptr = (int*)alloc((size_t)(N + 1) * 4);
    int* deg    = (int*)alloc((size_t)N * 4);
    int* ebuf   = (int*)alloc((size_t)E * 4);
    int* blocksum = (int*)alloc(1024 * 4);
    int* ccnt   = (int*)alloc(512 * 4);
    int* cbase  = (int*)alloc(513 * 4);
    int* ccur   = (int*)alloc(512 * 4);
    uint2* pairs = (uint2*)alloc((size_t)E * 8);
    __hip_bfloat16* Wt0  = (__hip_bfloat16*)alloc(256 * 256 * 2);
    __hip_bfloat16* Wt1  = (__hip_bfloat16*)alloc(256 * 128 * 2);
    __hip_bfloat16* Wtjk = (__hip_bfloat16*)alloc(128 * 256 * 2);
    __hip_bfloat16* yz = (__hip_bfloat16*)alloc((size_t)N * 256 * 2);
    __hip_bfloat16* h0 = (__hip_bfloat16*)alloc((size_t)N * 128 * 2);
    __hip_bfloat16* h1 = (__hip_bfloat16*)alloc((size_t)N * 128 * 2);
    float* feats = (float*)yz;   // yz dead after second agg; same byte size

    // dtype detection
    detect_kernel<<<1, 256, 0, stream>>>(ei, (const unsigned short*)x, flags);

    // CSR build v2 (two-level binned counting sort)
    (void)hipMemsetAsync(ccnt, 0, 512 * 4, stream);
    coarse_count<<<(E + 8191) / 8192, 256, 0, stream>>>(ei, E, flags, ccnt);
    coarse_scan<<<1, 256, 0, stream>>>(ccnt, cbase, ccur, NBINS);
    coarse_scatter<<<(E + 2047) / 2048, 256, 0, stream>>>(ei, E, flags, ccur, pairs, NBINS);
    bin_degree<<<NBINS, 256, 0, stream>>>(pairs, cbase, deg, N);
    int NB = (N + 511) / 512;
    scan_phaseA<<<NB, 256, 0, stream>>>(deg, blocksum, N);
    scan_phaseB<<<1, 256, 0, stream>>>(blocksum, NB, rowptr, N);
    scan_phaseC<<<NB, 256, 0, stream>>>(deg, blocksum, rowptr, N);
    bin_scatter<<<NBINS, 256, 0, stream>>>(pairs, cbase, rowptr, ebuf, N);

    // Weight transposes
    transpose_kernel<<<(256 * 128 + 255) / 256, 256, 0, stream>>>(Wnl0, Wt0, 256, 128, 256, flags);
    transpose_kernel<<<(256 * 128 + 255) / 256, 256, 0, stream>>>(Wr0,  Wt0 + 128 * 256, 256, 128, 256, flags);
    transpose_kernel<<<(128 * 128 + 255) / 256, 256, 0, stream>>>(Wnl1, Wt1, 128, 128, 128, flags);
    transpose_kernel<<<(128 * 128 + 255) / 256, 256, 0, stream>>>(Wr1,  Wt1 + 128 * 128, 128, 128, 128, flags);
    transpose_kernel<<<(256 * 128 + 255) / 256, 256, 0, stream>>>(Wjk,  Wtjk, 256, 128, 256, flags);

    int gblocks = (N + 127) / 128;    // 128 nodes per block
    int ablocks = (int)(((size_t)N * 64 + 255) / 256);

    // layer 0: project (y0 = x@Wnl0, z0 = x@Wr0) -> agg+LN+ReLU -> h0
    gemm_v5<8><<<gblocks, 512, 0, stream>>>(x, x, 256, 1, Wt0, nullptr, yz, 256, 0, N, 256, flags);
    agg_ln_relu<<<ablocks, 256, 0, stream>>>(yz, rowptr, ebuf, bnl0, g0, be0, h0, N, flags);

    // layer 1 (K=128)
    gemm_v5<4><<<gblocks, 512, 0, stream>>>(h0, h0, 128, 0, Wt1, nullptr, yz, 256, 0, N, 256, flags);
    agg_ln_relu<<<ablocks, 256, 0, stream>>>(yz, rowptr, ebuf, bnl1, g1, be1, h1, N, flags);

    // JK: feats = [h0|h1] @ Wjk + bjk   (K split 128/128), f32 output
    gemm_v5<8><<<gblocks, 512, 0, stream>>>(h0, h1, 128, 0, Wtjk, bjk, feats, 128, 1, N, 128, flags);

    // MLP head
    head_kernel<<<(N + 7) / 8, 256, 0, stream>>>(feats, Wh1, bh1, Wh2, bh2, d_out, N, flags);
}